// Round 6
// baseline (562.347 us; speedup 1.0000x reference)
//
#include <hip/hip_runtime.h>
#include <hip/hip_fp16.h>
#include <math.h>

#define NB_NODES 100000
#define NB_EDGES 1600000
#define NB_GRAPHS 1000
#define CAP 232
constexpr float GN_EPS = 1e-5f;

// ---- hist (fire-and-forget atomics) + gstart (blocks 0-3 ride along free) ----
__global__ void hist_gstart_k(const int* __restrict__ dst, int* __restrict__ deg_in,
                              const int* __restrict__ batch, int* __restrict__ gstart) {
    int tid = threadIdx.x;
    if (blockIdx.x < 4) {
        int g = blockIdx.x * 256 + tid;
        if (g <= NB_GRAPHS) {
            int lo = 0, hi = NB_NODES;
            while (lo < hi) {
                int mid = (lo + hi) >> 1;
                if (batch[mid] < g) lo = mid + 1; else hi = mid;
            }
            gstart[g] = lo;
        }
    }
    int base = blockIdx.x * 512 + tid;
    int e0 = base, e1 = base + 256;
    int d0 = (e0 < NB_EDGES) ? dst[e0] : -1;
    int d1 = (e1 < NB_EDGES) ? dst[e1] : -1;
    if (d0 >= 0) atomicAdd(&deg_in[d0], 1);   // no return -> no wait
    if (d1 >= 0) atomicAdd(&deg_in[d1], 1);
}

// ---------------- scanA + dinv ----------------
__global__ void scanA_k(const int* __restrict__ deg_in, int* __restrict__ bsums,
                        float* __restrict__ dinv) {
    __shared__ int red[256];
    int tid = threadIdx.x;
    int base = blockIdx.x * 1024 + tid * 4;
    int s = 0;
#pragma unroll
    for (int i = 0; i < 4; i++) {
        if (base + i < NB_NODES) {
            int d = deg_in[base + i];
            s += d;
            dinv[base + i] = rsqrtf((float)(d + 1));
        }
    }
    red[tid] = s;
    __syncthreads();
    for (int st = 128; st > 0; st >>= 1) {
        if (tid < st) red[tid] += red[tid + st];
        __syncthreads();
    }
    if (tid == 0) bsums[blockIdx.x] = red[0];
}

__global__ void scanB_k(const int* __restrict__ bsums, int* __restrict__ boffs) {
    __shared__ int s[128];
    int tid = threadIdx.x;
    int own = (tid < 98) ? bsums[tid] : 0;
    s[tid] = own;
    __syncthreads();
    for (int off = 1; off < 128; off <<= 1) {
        int t = (tid >= off) ? s[tid - off] : 0;
        __syncthreads();
        s[tid] += t;
        __syncthreads();
    }
    if (tid < 98) boffs[tid] = s[tid] - own;
}

__global__ void scanC_k(const int* __restrict__ deg_in, const int* __restrict__ boffs,
                        int* __restrict__ rowptr, int* __restrict__ cursor) {
    __shared__ int s[256];
    int tid = threadIdx.x;
    int base = blockIdx.x * 1024 + tid * 4;
    int v[4];
    int tsum = 0;
#pragma unroll
    for (int i = 0; i < 4; i++) {
        v[i] = (base + i < NB_NODES) ? deg_in[base + i] : 0;
        tsum += v[i];
    }
    s[tid] = tsum;
    __syncthreads();
    for (int off = 1; off < 256; off <<= 1) {
        int t = (tid >= off) ? s[tid - off] : 0;
        __syncthreads();
        s[tid] += t;
        __syncthreads();
    }
    int run = boffs[blockIdx.x] + s[tid] - tsum;
#pragma unroll
    for (int i = 0; i < 4; i++) {
        if (base + i < NB_NODES) { rowptr[base + i] = run; cursor[base + i] = run; }
        run += v[i];
    }
    if (blockIdx.x == 0 && tid == 0) rowptr[NB_NODES] = NB_EDGES;
}

// ---- fill: cursor atomic (rtn) + NT scatter; order within a dst is irrelevant ----
__global__ void csr_fill_k(const int* __restrict__ ei, int* __restrict__ cursor,
                           int* __restrict__ csr_src) {
    int base = blockIdx.x * 1024 + threadIdx.x;
#pragma unroll
    for (int t = 0; t < 4; t++) {
        int e = base + t * 256;
        if (e < NB_EDGES) {
            int sidx = ei[e];
            int d = ei[NB_EDGES + e];
            int pos = atomicAdd(&cursor[d], 1);
            __builtin_nontemporal_store(sidx, &csr_src[pos]);
        }
    }
}

// ---------------- fp16 helpers ----------------
union HU {
    uint4 u;
    __half2 h[4];
};

__device__ __forceinline__ void acc8(float* a, uint4 v) {
    HU x; x.u = v;
    float2 f0 = __half22float2(x.h[0]);
    float2 f1 = __half22float2(x.h[1]);
    float2 f2 = __half22float2(x.h[2]);
    float2 f3 = __half22float2(x.h[3]);
    a[0] += f0.x; a[1] += f0.y; a[2] += f1.x; a[3] += f1.y;
    a[4] += f2.x; a[5] += f2.y; a[6] += f3.x; a[7] += f3.y;
}

// --------- aggregate: 2 nodes per wave, 8 lanes x uint4, joint issue --------------
// hs rows prescaled by dinv[src]. out = relu(dinv[dst]*(self + sum_src) + bias), fp16
__global__ __launch_bounds__(256) void aggregate_h_k(const __half* __restrict__ hs,
    const int* __restrict__ rowptr, const int* __restrict__ csr_src,
    const float* __restrict__ dinv, const float* __restrict__ bias,
    __half* __restrict__ out) {
    const uint4* hsv = (const uint4*)hs;  // row = 8 uint4 (64 fp16)
    int wave = blockIdx.x * 4 + (threadIdx.x >> 6);
    int n0 = wave * 2, n1 = n0 + 1;
    int lane = threadIdx.x & 63;
    int f8 = lane & 7;   // 16B chunk: features [f8*8, f8*8+8)
    int e8 = lane >> 3;  // edge slot 0..7
    int s0 = rowptr[n0], e0 = rowptr[n0 + 1];
    int s1 = rowptr[n1], e1 = rowptr[n1 + 1];
    float A0[8] = {0.f,0.f,0.f,0.f,0.f,0.f,0.f,0.f};
    float B0[8] = {0.f,0.f,0.f,0.f,0.f,0.f,0.f,0.f};
    float A1[8] = {0.f,0.f,0.f,0.f,0.f,0.f,0.f,0.f};
    float B1[8] = {0.f,0.f,0.f,0.f,0.f,0.f,0.f,0.f};
    if (e8 == 0) acc8(A0, hsv[(size_t)n0 * 8 + f8]);  // self terms, counted once
    if (e8 == 1) acc8(A1, hsv[(size_t)n1 * 8 + f8]);
    int j0 = s0, j1 = s1;
    // joint phase: 4 gathers in flight per lane
    while (j0 + 16 <= e0 && j1 + 16 <= e1) {
        int u0 = csr_src[j0 + e8];
        int u1 = csr_src[j0 + 8 + e8];
        int v0 = csr_src[j1 + e8];
        int v1 = csr_src[j1 + 8 + e8];
        uint4 r0 = hsv[(size_t)u0 * 8 + f8];
        uint4 r1 = hsv[(size_t)u1 * 8 + f8];
        uint4 q0 = hsv[(size_t)v0 * 8 + f8];
        uint4 q1 = hsv[(size_t)v1 * 8 + f8];
        acc8(A0, r0); acc8(B0, r1); acc8(A1, q0); acc8(B1, q1);
        j0 += 16; j1 += 16;
    }
    // drain node0
    for (; j0 + 16 <= e0; j0 += 16) {
        int u0 = csr_src[j0 + e8], u1 = csr_src[j0 + 8 + e8];
        uint4 r0 = hsv[(size_t)u0 * 8 + f8], r1 = hsv[(size_t)u1 * 8 + f8];
        acc8(A0, r0); acc8(B0, r1);
    }
    if (j0 + 8 <= e0) {
        int u = csr_src[j0 + e8];
        acc8(A0, hsv[(size_t)u * 8 + f8]);
        j0 += 8;
    }
    if (j0 + e8 < e0) {
        int u = csr_src[j0 + e8];
        acc8(B0, hsv[(size_t)u * 8 + f8]);
    }
    // drain node1
    for (; j1 + 16 <= e1; j1 += 16) {
        int u0 = csr_src[j1 + e8], u1 = csr_src[j1 + 8 + e8];
        uint4 r0 = hsv[(size_t)u0 * 8 + f8], r1 = hsv[(size_t)u1 * 8 + f8];
        acc8(A1, r0); acc8(B1, r1);
    }
    if (j1 + 8 <= e1) {
        int u = csr_src[j1 + e8];
        acc8(A1, hsv[(size_t)u * 8 + f8]);
        j1 += 8;
    }
    if (j1 + e8 < e1) {
        int u = csr_src[j1 + e8];
        acc8(B1, hsv[(size_t)u * 8 + f8]);
    }
#pragma unroll
    for (int c = 0; c < 8; c++) {
        float t = A0[c] + B0[c];
        t += __shfl_xor(t, 8, 64);
        t += __shfl_xor(t, 16, 64);
        t += __shfl_xor(t, 32, 64);
        A0[c] = t;
        float u = A1[c] + B1[c];
        u += __shfl_xor(u, 8, 64);
        u += __shfl_xor(u, 16, 64);
        u += __shfl_xor(u, 32, 64);
        A1[c] = u;
    }
    if (e8 < 2) {
        int node = (e8 == 0) ? n0 : n1;
        const float* acc = (e8 == 0) ? A0 : A1;
        float dn = dinv[node];
        const float4* b4 = (const float4*)bias;
        float4 blo = b4[f8 * 2], bhi = b4[f8 * 2 + 1];
        float r[8];
        r[0] = fmaf(acc[0], dn, blo.x); r[1] = fmaf(acc[1], dn, blo.y);
        r[2] = fmaf(acc[2], dn, blo.z); r[3] = fmaf(acc[3], dn, blo.w);
        r[4] = fmaf(acc[4], dn, bhi.x); r[5] = fmaf(acc[5], dn, bhi.y);
        r[6] = fmaf(acc[6], dn, bhi.z); r[7] = fmaf(acc[7], dn, bhi.w);
#pragma unroll
        for (int c = 0; c < 8; c++) r[c] = r[c] > 0.f ? r[c] : 0.f;
        HU o;
        o.h[0] = __floats2half2_rn(r[0], r[1]);
        o.h[1] = __floats2half2_rn(r[2], r[3]);
        o.h[2] = __floats2half2_rn(r[4], r[5]);
        o.h[3] = __floats2half2_rn(r[6], r[7]);
        ((uint4*)out)[(size_t)node * 8 + f8] = o.u;
    }
}

// ------- normlin: GraphNorm(64) single-pass stats + linear 64x64 + dinv -----------
__global__ __launch_bounds__(512) void normlin_k(const __half* __restrict__ A,
    const int* __restrict__ gstart, const float* __restrict__ gw,
    const float* __restrict__ gb, const float* __restrict__ ga,
    const float* __restrict__ W, const float* __restrict__ dinv,
    __half* __restrict__ out) {
    __shared__ float sW[64 * 64];
    __shared__ float red[512], red2[512];
    __shared__ float sam[64], ssc[64];
    __shared__ float srow[8 * 64];
    int tid = threadIdx.x, lane = tid & 63, wid = tid >> 6;
    int g = blockIdx.x;
    int s = gstart[g], e = gstart[g + 1], cnt = e - s;
    float cntf = (float)(cnt > 1 ? cnt : 1);
    for (int i = tid; i < 64 * 64; i += 512) sW[i] = W[i];
    float sum = 0.f, sq = 0.f;
    for (int i = s + wid; i < e; i += 8) {
        float v = __half2float(A[(size_t)i * 64 + lane]);
        sum += v;
        sq = fmaf(v, v, sq);
    }
    red[tid] = sum; red2[tid] = sq;
    __syncthreads();
    for (int st = 4; st > 0; st >>= 1) {
        if (wid < st) { red[tid] += red[tid + st * 64]; red2[tid] += red2[tid + st * 64]; }
        __syncthreads();
    }
    if (tid < 64) {
        float m = red[tid] / cntf, q = red2[tid] / cntf;
        float am = ga[tid] * m;
        float var = q - 2.f * am * m + am * am;
        sam[tid] = am;
        ssc[tid] = gw[tid] * rsqrtf(var + GN_EPS);
    }
    __syncthreads();
    float am = sam[lane], sc = ssc[lane], bb = gb[lane];
    for (int i = s + wid; i < e; i += 8) {
        float nv = (__half2float(A[(size_t)i * 64 + lane]) - am) * sc + bb;
        srow[wid * 64 + lane] = nv;  // wave-synchronous: write then read within one wave
        float acc = 0.f;
#pragma unroll
        for (int k = 0; k < 64; k++) acc = fmaf(srow[wid * 64 + k], sW[k * 64 + lane], acc);
        out[(size_t)i * 64 + lane] = __float2half(acc * dinv[i]);
    }
}

// ---------------- layer0: GraphNorm(16) + linear 16->64 (block per graph) ---------
__device__ __forceinline__ void l0_body(float* rows, int cnt, int s,
    const float* __restrict__ x, const float* __restrict__ gw,
    const float* __restrict__ gb, const float* __restrict__ ga,
    const float* sW, const float* __restrict__ dinv, __half* __restrict__ hs_out,
    float* red, float* red2, float* sstat, float* sscale, int tid) {
    int f = tid & 15, r = tid >> 4;
    int lane = tid & 63, wid = tid >> 6;
    float cntf = (float)(cnt > 1 ? cnt : 1);
    float sum = 0.f, sq = 0.f;
    for (int i = r; i < cnt; i += 32) {
        float v = x[(size_t)(s + i) * 16 + f];
        rows[i * 16 + f] = v;
        sum += v;
        sq = fmaf(v, v, sq);
    }
    red[tid] = sum; red2[tid] = sq;
    __syncthreads();
    for (int st = 16; st > 0; st >>= 1) {
        if (r < st) { red[tid] += red[tid + st * 16]; red2[tid] += red2[tid + st * 16]; }
        __syncthreads();
    }
    if (tid < 16) {
        float m = red[tid] / cntf, q = red2[tid] / cntf;
        float am = ga[tid] * m;
        sstat[tid] = am;
        sscale[tid] = gw[tid] * rsqrtf(q - 2.f * am * m + am * am + GN_EPS);
    }
    __syncthreads();
    float am = sstat[f], sc = sscale[f], bb = gb[f];
    for (int i = r; i < cnt; i += 32) rows[i * 16 + f] = (rows[i * 16 + f] - am) * sc + bb;
    __syncthreads();
    for (int i = wid; i < cnt; i += 8) {
        float acc = 0.f;
#pragma unroll
        for (int k = 0; k < 16; k++) acc = fmaf(rows[i * 16 + k], sW[k * 64 + lane], acc);
        hs_out[(size_t)(s + i) * 64 + lane] = __float2half(acc * dinv[s + i]);
    }
}

__global__ __launch_bounds__(512) void layer0_k(const float* __restrict__ x,
    const int* __restrict__ gstart, const float* __restrict__ gw,
    const float* __restrict__ gb, const float* __restrict__ ga,
    const float* __restrict__ W, const float* __restrict__ dinv,
    __half* __restrict__ hs_out, float* __restrict__ spill16) {
    __shared__ float sRows[CAP * 16];
    __shared__ float sW[16 * 64];
    __shared__ float red[512], red2[512];
    __shared__ float sstat[16], sscale[16];
    int tid = threadIdx.x;
    int g = blockIdx.x;
    int s = gstart[g], e = gstart[g + 1], cnt = e - s;
    for (int i = tid; i < 16 * 64; i += 512) sW[i] = W[i];
    __syncthreads();
    if (cnt <= CAP)
        l0_body(sRows, cnt, s, x, gw, gb, ga, sW, dinv, hs_out, red, red2, sstat, sscale, tid);
    else
        l0_body(spill16 + (size_t)s * 16, cnt, s, x, gw, gb, ga, sW, dinv, hs_out, red, red2, sstat, sscale, tid);
}

// ---------------- Pool + MLP head + softmax: block per graph ----------------
__global__ void pool_head_k(const __half* __restrict__ x, const int* __restrict__ gstart,
                            const float* __restrict__ Wd, const float* __restrict__ bd,
                            const float* __restrict__ Wo, const float* __restrict__ bo,
                            float* __restrict__ out) {
    __shared__ float red[256];
    __shared__ float sp[64];
    __shared__ float sh[64];
    __shared__ float sl[2];
    int g = blockIdx.x;
    int s = gstart[g], e = gstart[g + 1];
    int cnt = e - s;
    float cntf = (float)(cnt > 1 ? cnt : 1);
    int tid = threadIdx.x;
    int f = tid & 63, r = tid >> 6;
    float sum = 0.f;
    for (int i = s + r; i < e; i += 4) sum += __half2float(x[(size_t)i * 64 + f]);
    red[tid] = sum;
    __syncthreads();
    for (int st = 2; st > 0; st >>= 1) {
        if (r < st) red[tid] += red[tid + st * 64];
        __syncthreads();
    }
    if (tid < 64) sp[tid] = red[tid] / cntf;
    __syncthreads();
    if (tid < 64) {
        float acc = bd[tid];
        for (int k = 0; k < 64; k++) acc = fmaf(sp[k], Wd[k * 64 + tid], acc);
        sh[tid] = acc > 0.f ? acc : 0.f;
    }
    __syncthreads();
    if (tid < 2) {
        float l = bo[tid];
        for (int k = 0; k < 64; k++) l = fmaf(sh[k], Wo[k * 2 + tid], l);
        sl[tid] = l;
    }
    __syncthreads();
    if (tid < 2) {
        float m = fmaxf(sl[0], sl[1]);
        float e0 = expf(sl[0] - m), e1 = expf(sl[1] - m);
        out[g * 2 + tid] = (tid == 0 ? e0 : e1) / (e0 + e1);
    }
}

extern "C" void kernel_launch(void* const* d_in, const int* in_sizes, int n_in,
                              void* d_out, int out_size, void* d_ws, size_t ws_size,
                              hipStream_t stream) {
    const float* x    = (const float*)d_in[0];
    const int* ei     = (const int*)d_in[1];
    const int* batch  = (const int*)d_in[2];
    const float* gn0w = (const float*)d_in[3];
    const float* gn0b = (const float*)d_in[4];
    const float* gn0a = (const float*)d_in[5];
    const float* W1   = (const float*)d_in[6];
    const float* b1   = (const float*)d_in[7];
    const float* gn1w = (const float*)d_in[8];
    const float* gn1b = (const float*)d_in[9];
    const float* gn1a = (const float*)d_in[10];
    const float* W2   = (const float*)d_in[11];
    const float* b2   = (const float*)d_in[12];
    const float* gn2w = (const float*)d_in[13];
    const float* gn2b = (const float*)d_in[14];
    const float* gn2a = (const float*)d_in[15];
    const float* W3   = (const float*)d_in[16];
    const float* b3   = (const float*)d_in[17];
    const float* Wd   = (const float*)d_in[18];
    const float* bd   = (const float*)d_in[19];
    const float* Wo   = (const float*)d_in[20];
    const float* bo   = (const float*)d_in[21];

    char* p = (char*)d_ws;
    auto alloc = [&](size_t bytes) -> void* {
        void* r = (void*)p;
        p += (bytes + 255) & ~(size_t)255;
        return r;
    };
    __half* A      = (__half*)alloc((size_t)NB_NODES * 64 * 2);
    __half* B      = (__half*)alloc((size_t)NB_NODES * 64 * 2);
    int* rowptr    = (int*)alloc((size_t)(NB_NODES + 1) * 4);
    int* deg_in    = (int*)alloc((size_t)NB_NODES * 4);
    int* cursor    = (int*)alloc((size_t)NB_NODES * 4);
    int* csr_src   = (int*)alloc((size_t)NB_EDGES * 4);
    float* dinv    = (float*)alloc((size_t)NB_NODES * 4);
    int* gstart    = (int*)alloc((size_t)(NB_GRAPHS + 1) * 4);
    int* bsums     = (int*)alloc(128 * 4);
    int* boffs     = (int*)alloc(128 * 4);
    float* spill16 = (float*)alloc((size_t)NB_NODES * 16 * 4);

    hipMemsetAsync(deg_in, 0, NB_NODES * 4, stream);

    hist_gstart_k<<<3125, 256, 0, stream>>>(ei + NB_EDGES, deg_in, batch, gstart);
    scanA_k<<<98, 256, 0, stream>>>(deg_in, bsums, dinv);
    scanB_k<<<1, 128, 0, stream>>>(bsums, boffs);
    scanC_k<<<98, 256, 0, stream>>>(deg_in, boffs, rowptr, cursor);
    csr_fill_k<<<1563, 256, 0, stream>>>(ei, cursor, csr_src);

    layer0_k<<<NB_GRAPHS, 512, 0, stream>>>(x, gstart, gn0w, gn0b, gn0a, W1, dinv, B, spill16);
    aggregate_h_k<<<12500, 256, 0, stream>>>(B, rowptr, csr_src, dinv, b1, A);
    normlin_k<<<NB_GRAPHS, 512, 0, stream>>>(A, gstart, gn1w, gn1b, gn1a, W2, dinv, B);
    aggregate_h_k<<<12500, 256, 0, stream>>>(B, rowptr, csr_src, dinv, b2, A);
    normlin_k<<<NB_GRAPHS, 512, 0, stream>>>(A, gstart, gn2w, gn2b, gn2a, W3, dinv, B);
    aggregate_h_k<<<12500, 256, 0, stream>>>(B, rowptr, csr_src, dinv, b3, A);
    pool_head_k<<<NB_GRAPHS, 256, 0, stream>>>(A, gstart, Wd, bd, Wo, bo, (float*)d_out);
}

// Round 7
// 415.938 us; speedup vs baseline: 1.3520x; 1.3520x over previous
//
#include <hip/hip_runtime.h>
#include <hip/hip_fp16.h>
#include <math.h>

#define NB_NODES 100000
#define NB_EDGES 1600000
#define NB_GRAPHS 1000
#define CAP 232
constexpr float GN_EPS = 1e-5f;

// ---- degree histogram (rank via atomic return) + gstart merged (blocks 0-3) ----
__global__ void hist_rank_gstart_k(const int* __restrict__ dst, int* __restrict__ deg_in,
                                   int* __restrict__ rk, const int* __restrict__ batch,
                                   int* __restrict__ gstart) {
    int tid = threadIdx.x;
    if (blockIdx.x < 4) {
        int g = blockIdx.x * 256 + tid;
        if (g <= NB_GRAPHS) {
            int lo = 0, hi = NB_NODES;
            while (lo < hi) {
                int mid = (lo + hi) >> 1;
                if (batch[mid] < g) lo = mid + 1; else hi = mid;
            }
            gstart[g] = lo;
        }
    }
    int base = blockIdx.x * 1024 + tid;
#pragma unroll
    for (int t = 0; t < 4; t++) {
        int e = base + t * 256;
        if (e < NB_EDGES) rk[e] = atomicAdd(&deg_in[dst[e]], 1);
    }
}

// ---------------- scanA + dinv ----------------
__global__ void scanA_k(const int* __restrict__ deg_in, int* __restrict__ bsums,
                        float* __restrict__ dinv) {
    __shared__ int red[256];
    int tid = threadIdx.x;
    int base = blockIdx.x * 1024 + tid * 4;
    int s = 0;
#pragma unroll
    for (int i = 0; i < 4; i++) {
        if (base + i < NB_NODES) {
            int d = deg_in[base + i];
            s += d;
            dinv[base + i] = rsqrtf((float)(d + 1));
        }
    }
    red[tid] = s;
    __syncthreads();
    for (int st = 128; st > 0; st >>= 1) {
        if (tid < st) red[tid] += red[tid + st];
        __syncthreads();
    }
    if (tid == 0) bsums[blockIdx.x] = red[0];
}

__global__ void scanB_k(const int* __restrict__ bsums, int* __restrict__ boffs) {
    __shared__ int s[128];
    int tid = threadIdx.x;
    int own = (tid < 98) ? bsums[tid] : 0;
    s[tid] = own;
    __syncthreads();
    for (int off = 1; off < 128; off <<= 1) {
        int t = (tid >= off) ? s[tid - off] : 0;
        __syncthreads();
        s[tid] += t;
        __syncthreads();
    }
    if (tid < 98) boffs[tid] = s[tid] - own;
}

__global__ void scanC_k(const int* __restrict__ deg_in, const int* __restrict__ boffs,
                        int* __restrict__ rowptr) {
    __shared__ int s[256];
    int tid = threadIdx.x;
    int base = blockIdx.x * 1024 + tid * 4;
    int v[4];
    int tsum = 0;
#pragma unroll
    for (int i = 0; i < 4; i++) {
        v[i] = (base + i < NB_NODES) ? deg_in[base + i] : 0;
        tsum += v[i];
    }
    s[tid] = tsum;
    __syncthreads();
    for (int off = 1; off < 256; off <<= 1) {
        int t = (tid >= off) ? s[tid - off] : 0;
        __syncthreads();
        s[tid] += t;
        __syncthreads();
    }
    int run = boffs[blockIdx.x] + s[tid] - tsum;
#pragma unroll
    for (int i = 0; i < 4; i++) {
        if (base + i < NB_NODES) rowptr[base + i] = run;
        run += v[i];
    }
    if (blockIdx.x == 0 && tid == 0) rowptr[NB_NODES] = NB_EDGES;
}

// ---- fill: pure scatter, position precomputed (rowptr[d] + rk[e]) ----
__global__ void csr_fill_k(const int* __restrict__ ei, const int* __restrict__ rowptr,
                           const int* __restrict__ rk, int* __restrict__ csr_src) {
    int base = blockIdx.x * 512 + threadIdx.x;
#pragma unroll
    for (int t = 0; t < 2; t++) {
        int e = base + t * 256;
        if (e < NB_EDGES) {
            int sidx = ei[e];
            int d = ei[NB_EDGES + e];
            csr_src[rowptr[d] + rk[e]] = sidx;
        }
    }
}

// ---------------- fp16 helpers ----------------
union HU {
    uint4 u;
    __half2 h[4];
};

__device__ __forceinline__ void acc8(float* a, uint4 v) {
    HU x; x.u = v;
    float2 f0 = __half22float2(x.h[0]);
    float2 f1 = __half22float2(x.h[1]);
    float2 f2 = __half22float2(x.h[2]);
    float2 f3 = __half22float2(x.h[3]);
    a[0] += f0.x; a[1] += f0.y; a[2] += f1.x; a[3] += f1.y;
    a[4] += f2.x; a[5] += f2.y; a[6] += f3.x; a[7] += f3.y;
}

// --------- aggregate: wave/node, 8 lanes x uint4, depth-2 software pipeline -------
// hs rows prescaled by dinv[src]. out = relu(dinv[dst]*(self + sum_src) + bias), fp16
// Edge blocks of 8 (one per e8 slot). Pipeline: while consuming block b, the gather
// for block b+1 and the index load for block b+2 are already in flight.
__global__ __launch_bounds__(256) void aggregate_h_k(const __half* __restrict__ hs,
    const int* __restrict__ rowptr, const int* __restrict__ csr_src,
    const float* __restrict__ dinv, const float* __restrict__ bias,
    __half* __restrict__ out) {
    const uint4* hsv = (const uint4*)hs;  // row = 8 uint4 (64 fp16)
    int node = blockIdx.x * 4 + (threadIdx.x >> 6);
    int lane = threadIdx.x & 63;
    int f8 = lane & 7;   // 16B chunk: features [f8*8, f8*8+8)
    int e8 = lane >> 3;  // edge slot 0..7
    int s = rowptr[node], e = rowptr[node + 1];
    int len = e - s;
    int nb = len >> 3;          // full 8-edge blocks
    int rem = len & 7;
    int tb = nb + (rem ? 1 : 0);  // total blocks (wave-uniform)
    int my = s + e8;
    float a[8] = {0.f, 0.f, 0.f, 0.f, 0.f, 0.f, 0.f, 0.f};
    if (e8 == 0) acc8(a, hsv[(size_t)node * 8 + f8]);  // self term
    const uint4 Z = {0u, 0u, 0u, 0u};
    // lane active in block b iff (b < nb) || (b == nb && e8 < rem)
    int i0 = -1, i1 = -1;
    if (tb > 0 && (0 < nb || e8 < rem)) i0 = csr_src[my];
    if (tb > 1 && (1 < nb || e8 < rem)) i1 = csr_src[my + 8];
    uint4 v0 = Z;
    if (i0 >= 0) v0 = hsv[(size_t)i0 * 8 + f8];
    for (int b = 0; b + 2 < tb; b++) {
        uint4 v1 = Z;
        if (i1 >= 0) v1 = hsv[(size_t)i1 * 8 + f8];          // gather block b+1
        int b2 = b + 2;
        int i2 = -1;
        if (b2 < nb || (b2 == nb && e8 < rem)) i2 = csr_src[my + b2 * 8];  // idx b+2
        if (i0 >= 0) acc8(a, v0);                             // consume block b
        v0 = v1; i0 = i1; i1 = i2;                            // rotate
    }
    if (tb > 0 && i0 >= 0) acc8(a, v0);
    if (tb > 1 && i1 >= 0) {
        uint4 v = hsv[(size_t)i1 * 8 + f8];
        acc8(a, v);
    }
#pragma unroll
    for (int c = 0; c < 8; c++) {
        float t = a[c];
        t += __shfl_xor(t, 8, 64);
        t += __shfl_xor(t, 16, 64);
        t += __shfl_xor(t, 32, 64);
        a[c] = t;
    }
    if (e8 == 0) {
        float dn = dinv[node];
        const float4* b4 = (const float4*)bias;
        float4 blo = b4[f8 * 2], bhi = b4[f8 * 2 + 1];
        float r[8];
        r[0] = fmaf(a[0], dn, blo.x); r[1] = fmaf(a[1], dn, blo.y);
        r[2] = fmaf(a[2], dn, blo.z); r[3] = fmaf(a[3], dn, blo.w);
        r[4] = fmaf(a[4], dn, bhi.x); r[5] = fmaf(a[5], dn, bhi.y);
        r[6] = fmaf(a[6], dn, bhi.z); r[7] = fmaf(a[7], dn, bhi.w);
#pragma unroll
        for (int c = 0; c < 8; c++) r[c] = r[c] > 0.f ? r[c] : 0.f;
        HU o;
        o.h[0] = __floats2half2_rn(r[0], r[1]);
        o.h[1] = __floats2half2_rn(r[2], r[3]);
        o.h[2] = __floats2half2_rn(r[4], r[5]);
        o.h[3] = __floats2half2_rn(r[6], r[7]);
        ((uint4*)out)[(size_t)node * 8 + f8] = o.u;
    }
}

// ------- normlin: GraphNorm(64) single-pass stats + linear 64x64 + dinv -----------
__global__ __launch_bounds__(512) void normlin_k(const __half* __restrict__ A,
    const int* __restrict__ gstart, const float* __restrict__ gw,
    const float* __restrict__ gb, const float* __restrict__ ga,
    const float* __restrict__ W, const float* __restrict__ dinv,
    __half* __restrict__ out) {
    __shared__ float sW[64 * 64];
    __shared__ float red[512], red2[512];
    __shared__ float sam[64], ssc[64];
    __shared__ float srow[8 * 64];
    int tid = threadIdx.x, lane = tid & 63, wid = tid >> 6;
    int g = blockIdx.x;
    int s = gstart[g], e = gstart[g + 1], cnt = e - s;
    float cntf = (float)(cnt > 1 ? cnt : 1);
    for (int i = tid; i < 64 * 64; i += 512) sW[i] = W[i];
    float sum = 0.f, sq = 0.f;
    for (int i = s + wid; i < e; i += 8) {
        float v = __half2float(A[(size_t)i * 64 + lane]);
        sum += v;
        sq = fmaf(v, v, sq);
    }
    red[tid] = sum; red2[tid] = sq;
    __syncthreads();
    for (int st = 4; st > 0; st >>= 1) {
        if (wid < st) { red[tid] += red[tid + st * 64]; red2[tid] += red2[tid + st * 64]; }
        __syncthreads();
    }
    if (tid < 64) {
        float m = red[tid] / cntf, q = red2[tid] / cntf;
        float am = ga[tid] * m;
        float var = q - 2.f * am * m + am * am;
        sam[tid] = am;
        ssc[tid] = gw[tid] * rsqrtf(var + GN_EPS);
    }
    __syncthreads();
    float am = sam[lane], sc = ssc[lane], bb = gb[lane];
    for (int i = s + wid; i < e; i += 8) {
        float nv = (__half2float(A[(size_t)i * 64 + lane]) - am) * sc + bb;
        srow[wid * 64 + lane] = nv;  // wave-synchronous: write then read within one wave
        float acc = 0.f;
#pragma unroll
        for (int k = 0; k < 64; k++) acc = fmaf(srow[wid * 64 + k], sW[k * 64 + lane], acc);
        out[(size_t)i * 64 + lane] = __float2half(acc * dinv[i]);
    }
}

// ---------------- layer0: GraphNorm(16) + linear 16->64 (block per graph) ---------
__device__ __forceinline__ void l0_body(float* rows, int cnt, int s,
    const float* __restrict__ x, const float* __restrict__ gw,
    const float* __restrict__ gb, const float* __restrict__ ga,
    const float* sW, const float* __restrict__ dinv, __half* __restrict__ hs_out,
    float* red, float* red2, float* sstat, float* sscale, int tid) {
    int f = tid & 15, r = tid >> 4;
    int lane = tid & 63, wid = tid >> 6;
    float cntf = (float)(cnt > 1 ? cnt : 1);
    float sum = 0.f, sq = 0.f;
    for (int i = r; i < cnt; i += 32) {
        float v = x[(size_t)(s + i) * 16 + f];
        rows[i * 16 + f] = v;
        sum += v;
        sq = fmaf(v, v, sq);
    }
    red[tid] = sum; red2[tid] = sq;
    __syncthreads();
    for (int st = 16; st > 0; st >>= 1) {
        if (r < st) { red[tid] += red[tid + st * 16]; red2[tid] += red2[tid + st * 16]; }
        __syncthreads();
    }
    if (tid < 16) {
        float m = red[tid] / cntf, q = red2[tid] / cntf;
        float am = ga[tid] * m;
        sstat[tid] = am;
        sscale[tid] = gw[tid] * rsqrtf(q - 2.f * am * m + am * am + GN_EPS);
    }
    __syncthreads();
    float am = sstat[f], sc = sscale[f], bb = gb[f];
    for (int i = r; i < cnt; i += 32) rows[i * 16 + f] = (rows[i * 16 + f] - am) * sc + bb;
    __syncthreads();
    for (int i = wid; i < cnt; i += 8) {
        float acc = 0.f;
#pragma unroll
        for (int k = 0; k < 16; k++) acc = fmaf(rows[i * 16 + k], sW[k * 64 + lane], acc);
        hs_out[(size_t)(s + i) * 64 + lane] = __float2half(acc * dinv[s + i]);
    }
}

__global__ __launch_bounds__(512) void layer0_k(const float* __restrict__ x,
    const int* __restrict__ gstart, const float* __restrict__ gw,
    const float* __restrict__ gb, const float* __restrict__ ga,
    const float* __restrict__ W, const float* __restrict__ dinv,
    __half* __restrict__ hs_out, float* __restrict__ spill16) {
    __shared__ float sRows[CAP * 16];
    __shared__ float sW[16 * 64];
    __shared__ float red[512], red2[512];
    __shared__ float sstat[16], sscale[16];
    int tid = threadIdx.x;
    int g = blockIdx.x;
    int s = gstart[g], e = gstart[g + 1], cnt = e - s;
    for (int i = tid; i < 16 * 64; i += 512) sW[i] = W[i];
    __syncthreads();
    if (cnt <= CAP)
        l0_body(sRows, cnt, s, x, gw, gb, ga, sW, dinv, hs_out, red, red2, sstat, sscale, tid);
    else
        l0_body(spill16 + (size_t)s * 16, cnt, s, x, gw, gb, ga, sW, dinv, hs_out, red, red2, sstat, sscale, tid);
}

// ---------------- Pool + MLP head + softmax: block per graph ----------------
__global__ void pool_head_k(const __half* __restrict__ x, const int* __restrict__ gstart,
                            const float* __restrict__ Wd, const float* __restrict__ bd,
                            const float* __restrict__ Wo, const float* __restrict__ bo,
                            float* __restrict__ out) {
    __shared__ float red[256];
    __shared__ float sp[64];
    __shared__ float sh[64];
    __shared__ float sl[2];
    int g = blockIdx.x;
    int s = gstart[g], e = gstart[g + 1];
    int cnt = e - s;
    float cntf = (float)(cnt > 1 ? cnt : 1);
    int tid = threadIdx.x;
    int f = tid & 63, r = tid >> 6;
    float sum = 0.f;
    for (int i = s + r; i < e; i += 4) sum += __half2float(x[(size_t)i * 64 + f]);
    red[tid] = sum;
    __syncthreads();
    for (int st = 2; st > 0; st >>= 1) {
        if (r < st) red[tid] += red[tid + st * 64];
        __syncthreads();
    }
    if (tid < 64) sp[tid] = red[tid] / cntf;
    __syncthreads();
    if (tid < 64) {
        float acc = bd[tid];
        for (int k = 0; k < 64; k++) acc = fmaf(sp[k], Wd[k * 64 + tid], acc);
        sh[tid] = acc > 0.f ? acc : 0.f;
    }
    __syncthreads();
    if (tid < 2) {
        float l = bo[tid];
        for (int k = 0; k < 64; k++) l = fmaf(sh[k], Wo[k * 2 + tid], l);
        sl[tid] = l;
    }
    __syncthreads();
    if (tid < 2) {
        float m = fmaxf(sl[0], sl[1]);
        float e0 = expf(sl[0] - m), e1 = expf(sl[1] - m);
        out[g * 2 + tid] = (tid == 0 ? e0 : e1) / (e0 + e1);
    }
}

extern "C" void kernel_launch(void* const* d_in, const int* in_sizes, int n_in,
                              void* d_out, int out_size, void* d_ws, size_t ws_size,
                              hipStream_t stream) {
    const float* x    = (const float*)d_in[0];
    const int* ei     = (const int*)d_in[1];
    const int* batch  = (const int*)d_in[2];
    const float* gn0w = (const float*)d_in[3];
    const float* gn0b = (const float*)d_in[4];
    const float* gn0a = (const float*)d_in[5];
    const float* W1   = (const float*)d_in[6];
    const float* b1   = (const float*)d_in[7];
    const float* gn1w = (const float*)d_in[8];
    const float* gn1b = (const float*)d_in[9];
    const float* gn1a = (const float*)d_in[10];
    const float* W2   = (const float*)d_in[11];
    const float* b2   = (const float*)d_in[12];
    const float* gn2w = (const float*)d_in[13];
    const float* gn2b = (const float*)d_in[14];
    const float* gn2a = (const float*)d_in[15];
    const float* W3   = (const float*)d_in[16];
    const float* b3   = (const float*)d_in[17];
    const float* Wd   = (const float*)d_in[18];
    const float* bd   = (const float*)d_in[19];
    const float* Wo   = (const float*)d_in[20];
    const float* bo   = (const float*)d_in[21];

    char* p = (char*)d_ws;
    auto alloc = [&](size_t bytes) -> void* {
        void* r = (void*)p;
        p += (bytes + 255) & ~(size_t)255;
        return r;
    };
    __half* A      = (__half*)alloc((size_t)NB_NODES * 64 * 2);
    __half* B      = (__half*)alloc((size_t)NB_NODES * 64 * 2);
    int* rowptr    = (int*)alloc((size_t)(NB_NODES + 1) * 4);
    int* deg_in    = (int*)alloc((size_t)NB_NODES * 4);
    int* rk        = (int*)alloc((size_t)NB_EDGES * 4);
    int* csr_src   = (int*)alloc((size_t)NB_EDGES * 4);
    float* dinv    = (float*)alloc((size_t)NB_NODES * 4);
    int* gstart    = (int*)alloc((size_t)(NB_GRAPHS + 1) * 4);
    int* bsums     = (int*)alloc(128 * 4);
    int* boffs     = (int*)alloc(128 * 4);
    float* spill16 = (float*)alloc((size_t)NB_NODES * 16 * 4);

    hipMemsetAsync(deg_in, 0, NB_NODES * 4, stream);

    hist_rank_gstart_k<<<1563, 256, 0, stream>>>(ei + NB_EDGES, deg_in, rk, batch, gstart);
    scanA_k<<<98, 256, 0, stream>>>(deg_in, bsums, dinv);
    scanB_k<<<1, 128, 0, stream>>>(bsums, boffs);
    scanC_k<<<98, 256, 0, stream>>>(deg_in, boffs, rowptr);
    csr_fill_k<<<3125, 256, 0, stream>>>(ei, rowptr, rk, csr_src);

    layer0_k<<<NB_GRAPHS, 512, 0, stream>>>(x, gstart, gn0w, gn0b, gn0a, W1, dinv, B, spill16);
    aggregate_h_k<<<25000, 256, 0, stream>>>(B, rowptr, csr_src, dinv, b1, A);
    normlin_k<<<NB_GRAPHS, 512, 0, stream>>>(A, gstart, gn1w, gn1b, gn1a, W2, dinv, B);
    aggregate_h_k<<<25000, 256, 0, stream>>>(B, rowptr, csr_src, dinv, b2, A);
    normlin_k<<<NB_GRAPHS, 512, 0, stream>>>(A, gstart, gn2w, gn2b, gn2a, W3, dinv, B);
    aggregate_h_k<<<25000, 256, 0, stream>>>(B, rowptr, csr_src, dinv, b3, A);
    pool_head_k<<<NB_GRAPHS, 256, 0, stream>>>(A, gstart, Wd, bd, Wo, bo, (float*)d_out);
}

// Round 8
// 351.730 us; speedup vs baseline: 1.5988x; 1.1825x over previous
//
#include <hip/hip_runtime.h>
#include <hip/hip_fp16.h>
#include <math.h>

#define NB_NODES 100000
#define NB_EDGES 1600000
#define NB_GRAPHS 1000
#define CAP 232
#define NBLK1 400      // coarse pass blocks
#define CHUNK 4000     // edges per coarse block (NBLK1*CHUNK == NB_EDGES)
#define NBUCK 391      // ceil(NB_NODES/256) coarse buckets (dst >> 8)
#define BCAP 4608      // max edges per bucket (mean 4096, sigma 64, +8 sigma)
constexpr float GN_EPS = 1e-5f;

// ---- K1: per-block LDS histogram over coarse buckets + gstart (blocks 0-3) ----
__global__ __launch_bounds__(256) void k1_hist(const int* __restrict__ dst,
    int* __restrict__ hist, const int* __restrict__ batch, int* __restrict__ gstart) {
    __shared__ int h[NBUCK];
    int tid = threadIdx.x;
    for (int i = tid; i < NBUCK; i += 256) h[i] = 0;
    if (blockIdx.x < 4) {
        int g = blockIdx.x * 256 + tid;
        if (g <= NB_GRAPHS) {
            int lo = 0, hi = NB_NODES;
            while (lo < hi) {
                int mid = (lo + hi) >> 1;
                if (batch[mid] < g) lo = mid + 1; else hi = mid;
            }
            gstart[g] = lo;
        }
    }
    __syncthreads();
    int base = blockIdx.x * CHUNK;
    for (int i = tid; i < CHUNK; i += 256) atomicAdd(&h[dst[base + i] >> 8], 1);
    __syncthreads();
    for (int i = tid; i < NBUCK; i += 256) hist[blockIdx.x * NBUCK + i] = h[i];
}

// ---- K2a: per bucket, exclusive scan across the 400 blocks; emit totals ----
__global__ __launch_bounds__(512) void k2a_scan(int* __restrict__ hist,
                                                int* __restrict__ total) {
    __shared__ int s[512];
    int b = blockIdx.x;  // bucket
    int tid = threadIdx.x;
    int v = (tid < NBLK1) ? hist[tid * NBUCK + b] : 0;
    s[tid] = v;
    __syncthreads();
    for (int o = 1; o < 512; o <<= 1) {
        int t = (tid >= o) ? s[tid - o] : 0;
        __syncthreads();
        s[tid] += t;
        __syncthreads();
    }
    if (tid < NBLK1) hist[tid * NBUCK + b] = s[tid] - v;  // exclusive prefix in place
    if (tid == 511) total[b] = s[511];
}

// ---- K2b: exclusive scan of bucket totals -> base[NBUCK+1] ----
__global__ __launch_bounds__(512) void k2b_scan(const int* __restrict__ total,
                                                int* __restrict__ base) {
    __shared__ int s[512];
    int tid = threadIdx.x;
    int v = (tid < NBUCK) ? total[tid] : 0;
    s[tid] = v;
    __syncthreads();
    for (int o = 1; o < 512; o <<= 1) {
        int t = (tid >= o) ? s[tid - o] : 0;
        __syncthreads();
        s[tid] += t;
        __syncthreads();
    }
    if (tid < NBUCK) base[tid] = s[tid] - v;
    if (tid == NBUCK) base[NBUCK] = NB_EDGES;
}

// ---- K3: scatter packed edges into bucket-contiguous runs (LDS cursors) ----
__global__ __launch_bounds__(256) void k3_scatter(const int* __restrict__ ei,
    const int* __restrict__ hist, const int* __restrict__ base,
    unsigned int* __restrict__ ebuf) {
    __shared__ int cur[NBUCK];
    int tid = threadIdx.x;
    for (int i = tid; i < NBUCK; i += 256)
        cur[i] = base[i] + hist[blockIdx.x * NBUCK + i];
    __syncthreads();
    int eb = blockIdx.x * CHUNK;
    for (int i = tid; i < CHUNK; i += 256) {
        int e = eb + i;
        int sidx = ei[e];
        int d = ei[NB_EDGES + e];
        int pos = atomicAdd(&cur[d >> 8], 1);
        ebuf[pos] = (unsigned int)sidx | ((unsigned int)(d & 255) << 24);
    }
}

// ---- K4: per-bucket fine CSR in LDS; coalesced csr_src/rowptr/dinv writes ----
__global__ __launch_bounds__(256) void k4_fine(const unsigned int* __restrict__ ebuf,
    const int* __restrict__ base, int* __restrict__ csr_src, int* __restrict__ rowptr,
    float* __restrict__ dinv) {
    __shared__ unsigned int epk[BCAP];
    __shared__ int outb[BCAP];
    __shared__ int cnt[256];
    __shared__ int sbuf[256];
    __shared__ int cur2[256];
    int b = blockIdx.x;
    int tid = threadIdx.x;
    int eb = base[b], ee = base[b + 1];
    int m = ee - eb;
    if (m > BCAP) m = BCAP;  // memory-safety clamp (never expected)
    for (int i = tid; i < m; i += 256) epk[i] = ebuf[eb + i];
    cnt[tid] = 0;
    __syncthreads();
    for (int i = tid; i < m; i += 256) atomicAdd(&cnt[epk[i] >> 24], 1);
    __syncthreads();
    int c = cnt[tid];
    sbuf[tid] = c;
    __syncthreads();
    for (int o = 1; o < 256; o <<= 1) {
        int t = (tid >= o) ? sbuf[tid - o] : 0;
        __syncthreads();
        sbuf[tid] += t;
        __syncthreads();
    }
    int off = sbuf[tid] - c;  // exclusive scan
    cur2[tid] = off;
    __syncthreads();
    for (int i = tid; i < m; i += 256) {
        unsigned int p = epk[i];
        int r = atomicAdd(&cur2[p >> 24], 1);
        outb[r] = (int)(p & 0x00FFFFFFu);
    }
    __syncthreads();
    for (int i = tid; i < m; i += 256) csr_src[eb + i] = outb[i];
    int node = b * 256 + tid;
    if (node < NB_NODES) {
        rowptr[node] = eb + off;
        dinv[node] = rsqrtf((float)(c + 1));
    }
    if (b == 0 && tid == 0) rowptr[NB_NODES] = NB_EDGES;
}

// ---------------- fp16 helpers ----------------
union HU {
    uint4 u;
    __half2 h[4];
};

__device__ __forceinline__ void acc8(float* a, uint4 v) {
    HU x; x.u = v;
    float2 f0 = __half22float2(x.h[0]);
    float2 f1 = __half22float2(x.h[1]);
    float2 f2 = __half22float2(x.h[2]);
    float2 f3 = __half22float2(x.h[3]);
    a[0] += f0.x; a[1] += f0.y; a[2] += f1.x; a[3] += f1.y;
    a[4] += f2.x; a[5] += f2.y; a[6] += f3.x; a[7] += f3.y;
}

// --------- aggregate: wave/node, 8 lanes x uint4, depth-2 software pipeline -------
__global__ __launch_bounds__(256) void aggregate_h_k(const __half* __restrict__ hs,
    const int* __restrict__ rowptr, const int* __restrict__ csr_src,
    const float* __restrict__ dinv, const float* __restrict__ bias,
    __half* __restrict__ out) {
    const uint4* hsv = (const uint4*)hs;  // row = 8 uint4 (64 fp16)
    int node = blockIdx.x * 4 + (threadIdx.x >> 6);
    int lane = threadIdx.x & 63;
    int f8 = lane & 7;   // 16B chunk: features [f8*8, f8*8+8)
    int e8 = lane >> 3;  // edge slot 0..7
    int s = rowptr[node], e = rowptr[node + 1];
    int len = e - s;
    int nb = len >> 3;
    int rem = len & 7;
    int tb = nb + (rem ? 1 : 0);
    int my = s + e8;
    float a[8] = {0.f, 0.f, 0.f, 0.f, 0.f, 0.f, 0.f, 0.f};
    if (e8 == 0) acc8(a, hsv[(size_t)node * 8 + f8]);  // self term
    const uint4 Z = {0u, 0u, 0u, 0u};
    int i0 = -1, i1 = -1;
    if (tb > 0 && (0 < nb || e8 < rem)) i0 = csr_src[my];
    if (tb > 1 && (1 < nb || e8 < rem)) i1 = csr_src[my + 8];
    uint4 v0 = Z;
    if (i0 >= 0) v0 = hsv[(size_t)i0 * 8 + f8];
    for (int b = 0; b + 2 < tb; b++) {
        uint4 v1 = Z;
        if (i1 >= 0) v1 = hsv[(size_t)i1 * 8 + f8];
        int b2 = b + 2;
        int i2 = -1;
        if (b2 < nb || (b2 == nb && e8 < rem)) i2 = csr_src[my + b2 * 8];
        if (i0 >= 0) acc8(a, v0);
        v0 = v1; i0 = i1; i1 = i2;
    }
    if (tb > 0 && i0 >= 0) acc8(a, v0);
    if (tb > 1 && i1 >= 0) {
        uint4 v = hsv[(size_t)i1 * 8 + f8];
        acc8(a, v);
    }
#pragma unroll
    for (int c = 0; c < 8; c++) {
        float t = a[c];
        t += __shfl_xor(t, 8, 64);
        t += __shfl_xor(t, 16, 64);
        t += __shfl_xor(t, 32, 64);
        a[c] = t;
    }
    if (e8 == 0) {
        float dn = dinv[node];
        const float4* b4 = (const float4*)bias;
        float4 blo = b4[f8 * 2], bhi = b4[f8 * 2 + 1];
        float r[8];
        r[0] = fmaf(a[0], dn, blo.x); r[1] = fmaf(a[1], dn, blo.y);
        r[2] = fmaf(a[2], dn, blo.z); r[3] = fmaf(a[3], dn, blo.w);
        r[4] = fmaf(a[4], dn, bhi.x); r[5] = fmaf(a[5], dn, bhi.y);
        r[6] = fmaf(a[6], dn, bhi.z); r[7] = fmaf(a[7], dn, bhi.w);
#pragma unroll
        for (int c = 0; c < 8; c++) r[c] = r[c] > 0.f ? r[c] : 0.f;
        HU o;
        o.h[0] = __floats2half2_rn(r[0], r[1]);
        o.h[1] = __floats2half2_rn(r[2], r[3]);
        o.h[2] = __floats2half2_rn(r[4], r[5]);
        o.h[3] = __floats2half2_rn(r[6], r[7]);
        ((uint4*)out)[(size_t)node * 8 + f8] = o.u;
    }
}

// ------- normlin: GraphNorm(64) single-pass stats + linear 64x64 + dinv -----------
__global__ __launch_bounds__(512) void normlin_k(const __half* __restrict__ A,
    const int* __restrict__ gstart, const float* __restrict__ gw,
    const float* __restrict__ gb, const float* __restrict__ ga,
    const float* __restrict__ W, const float* __restrict__ dinv,
    __half* __restrict__ out) {
    __shared__ float sW[64 * 64];
    __shared__ float red[512], red2[512];
    __shared__ float sam[64], ssc[64];
    __shared__ float srow[8 * 64];
    int tid = threadIdx.x, lane = tid & 63, wid = tid >> 6;
    int g = blockIdx.x;
    int s = gstart[g], e = gstart[g + 1], cnt = e - s;
    float cntf = (float)(cnt > 1 ? cnt : 1);
    for (int i = tid; i < 64 * 64; i += 512) sW[i] = W[i];
    float sum = 0.f, sq = 0.f;
    for (int i = s + wid; i < e; i += 8) {
        float v = __half2float(A[(size_t)i * 64 + lane]);
        sum += v;
        sq = fmaf(v, v, sq);
    }
    red[tid] = sum; red2[tid] = sq;
    __syncthreads();
    for (int st = 4; st > 0; st >>= 1) {
        if (wid < st) { red[tid] += red[tid + st * 64]; red2[tid] += red2[tid + st * 64]; }
        __syncthreads();
    }
    if (tid < 64) {
        float m = red[tid] / cntf, q = red2[tid] / cntf;
        float am = ga[tid] * m;
        float var = q - 2.f * am * m + am * am;
        sam[tid] = am;
        ssc[tid] = gw[tid] * rsqrtf(var + GN_EPS);
    }
    __syncthreads();
    float am = sam[lane], sc = ssc[lane], bb = gb[lane];
    for (int i = s + wid; i < e; i += 8) {
        float nv = (__half2float(A[(size_t)i * 64 + lane]) - am) * sc + bb;
        srow[wid * 64 + lane] = nv;
        float acc = 0.f;
#pragma unroll
        for (int k = 0; k < 64; k++) acc = fmaf(srow[wid * 64 + k], sW[k * 64 + lane], acc);
        out[(size_t)i * 64 + lane] = __float2half(acc * dinv[i]);
    }
}

// ---------------- layer0: GraphNorm(16) + linear 16->64 (block per graph) ---------
__device__ __forceinline__ void l0_body(float* rows, int cnt, int s,
    const float* __restrict__ x, const float* __restrict__ gw,
    const float* __restrict__ gb, const float* __restrict__ ga,
    const float* sW, const float* __restrict__ dinv, __half* __restrict__ hs_out,
    float* red, float* red2, float* sstat, float* sscale, int tid) {
    int f = tid & 15, r = tid >> 4;
    int lane = tid & 63, wid = tid >> 6;
    float cntf = (float)(cnt > 1 ? cnt : 1);
    float sum = 0.f, sq = 0.f;
    for (int i = r; i < cnt; i += 32) {
        float v = x[(size_t)(s + i) * 16 + f];
        rows[i * 16 + f] = v;
        sum += v;
        sq = fmaf(v, v, sq);
    }
    red[tid] = sum; red2[tid] = sq;
    __syncthreads();
    for (int st = 16; st > 0; st >>= 1) {
        if (r < st) { red[tid] += red[tid + st * 16]; red2[tid] += red2[tid + st * 16]; }
        __syncthreads();
    }
    if (tid < 16) {
        float m = red[tid] / cntf, q = red2[tid] / cntf;
        float am = ga[tid] * m;
        sstat[tid] = am;
        sscale[tid] = gw[tid] * rsqrtf(q - 2.f * am * m + am * am + GN_EPS);
    }
    __syncthreads();
    float am = sstat[f], sc = sscale[f], bb = gb[f];
    for (int i = r; i < cnt; i += 32) rows[i * 16 + f] = (rows[i * 16 + f] - am) * sc + bb;
    __syncthreads();
    for (int i = wid; i < cnt; i += 8) {
        float acc = 0.f;
#pragma unroll
        for (int k = 0; k < 16; k++) acc = fmaf(rows[i * 16 + k], sW[k * 64 + lane], acc);
        hs_out[(size_t)(s + i) * 64 + lane] = __float2half(acc * dinv[s + i]);
    }
}

__global__ __launch_bounds__(512) void layer0_k(const float* __restrict__ x,
    const int* __restrict__ gstart, const float* __restrict__ gw,
    const float* __restrict__ gb, const float* __restrict__ ga,
    const float* __restrict__ W, const float* __restrict__ dinv,
    __half* __restrict__ hs_out, float* __restrict__ spill16) {
    __shared__ float sRows[CAP * 16];
    __shared__ float sW[16 * 64];
    __shared__ float red[512], red2[512];
    __shared__ float sstat[16], sscale[16];
    int tid = threadIdx.x;
    int g = blockIdx.x;
    int s = gstart[g], e = gstart[g + 1], cnt = e - s;
    for (int i = tid; i < 16 * 64; i += 512) sW[i] = W[i];
    __syncthreads();
    if (cnt <= CAP)
        l0_body(sRows, cnt, s, x, gw, gb, ga, sW, dinv, hs_out, red, red2, sstat, sscale, tid);
    else
        l0_body(spill16 + (size_t)s * 16, cnt, s, x, gw, gb, ga, sW, dinv, hs_out, red, red2, sstat, sscale, tid);
}

// ---------------- Pool + MLP head + softmax: block per graph ----------------
__global__ void pool_head_k(const __half* __restrict__ x, const int* __restrict__ gstart,
                            const float* __restrict__ Wd, const float* __restrict__ bd,
                            const float* __restrict__ Wo, const float* __restrict__ bo,
                            float* __restrict__ out) {
    __shared__ float red[256];
    __shared__ float sp[64];
    __shared__ float sh[64];
    __shared__ float sl[2];
    int g = blockIdx.x;
    int s = gstart[g], e = gstart[g + 1];
    int cnt = e - s;
    float cntf = (float)(cnt > 1 ? cnt : 1);
    int tid = threadIdx.x;
    int f = tid & 63, r = tid >> 6;
    float sum = 0.f;
    for (int i = s + r; i < e; i += 4) sum += __half2float(x[(size_t)i * 64 + f]);
    red[tid] = sum;
    __syncthreads();
    for (int st = 2; st > 0; st >>= 1) {
        if (r < st) red[tid] += red[tid + st * 64];
        __syncthreads();
    }
    if (tid < 64) sp[tid] = red[tid] / cntf;
    __syncthreads();
    if (tid < 64) {
        float acc = bd[tid];
        for (int k = 0; k < 64; k++) acc = fmaf(sp[k], Wd[k * 64 + tid], acc);
        sh[tid] = acc > 0.f ? acc : 0.f;
    }
    __syncthreads();
    if (tid < 2) {
        float l = bo[tid];
        for (int k = 0; k < 64; k++) l = fmaf(sh[k], Wo[k * 2 + tid], l);
        sl[tid] = l;
    }
    __syncthreads();
    if (tid < 2) {
        float m = fmaxf(sl[0], sl[1]);
        float e0 = expf(sl[0] - m), e1 = expf(sl[1] - m);
        out[g * 2 + tid] = (tid == 0 ? e0 : e1) / (e0 + e1);
    }
}

extern "C" void kernel_launch(void* const* d_in, const int* in_sizes, int n_in,
                              void* d_out, int out_size, void* d_ws, size_t ws_size,
                              hipStream_t stream) {
    const float* x    = (const float*)d_in[0];
    const int* ei     = (const int*)d_in[1];
    const int* batch  = (const int*)d_in[2];
    const float* gn0w = (const float*)d_in[3];
    const float* gn0b = (const float*)d_in[4];
    const float* gn0a = (const float*)d_in[5];
    const float* W1   = (const float*)d_in[6];
    const float* b1   = (const float*)d_in[7];
    const float* gn1w = (const float*)d_in[8];
    const float* gn1b = (const float*)d_in[9];
    const float* gn1a = (const float*)d_in[10];
    const float* W2   = (const float*)d_in[11];
    const float* b2   = (const float*)d_in[12];
    const float* gn2w = (const float*)d_in[13];
    const float* gn2b = (const float*)d_in[14];
    const float* gn2a = (const float*)d_in[15];
    const float* W3   = (const float*)d_in[16];
    const float* b3   = (const float*)d_in[17];
    const float* Wd   = (const float*)d_in[18];
    const float* bd   = (const float*)d_in[19];
    const float* Wo   = (const float*)d_in[20];
    const float* bo   = (const float*)d_in[21];

    char* p = (char*)d_ws;
    auto alloc = [&](size_t bytes) -> void* {
        void* r = (void*)p;
        p += (bytes + 255) & ~(size_t)255;
        return r;
    };
    __half* A        = (__half*)alloc((size_t)NB_NODES * 64 * 2);
    __half* B        = (__half*)alloc((size_t)NB_NODES * 64 * 2);
    int* rowptr      = (int*)alloc((size_t)(NB_NODES + 1) * 4);
    unsigned* ebuf   = (unsigned*)alloc((size_t)NB_EDGES * 4);
    int* csr_src     = (int*)alloc((size_t)NB_EDGES * 4);
    int* hist        = (int*)alloc((size_t)NBLK1 * NBUCK * 4);
    int* total       = (int*)alloc((size_t)NBUCK * 4);
    int* basearr     = (int*)alloc((size_t)(NBUCK + 1) * 4);
    float* dinv      = (float*)alloc((size_t)NB_NODES * 4);
    int* gstart      = (int*)alloc((size_t)(NB_GRAPHS + 1) * 4);
    float* spill16   = (float*)alloc((size_t)NB_NODES * 16 * 4);

    k1_hist<<<NBLK1, 256, 0, stream>>>(ei + NB_EDGES, hist, batch, gstart);
    k2a_scan<<<NBUCK, 512, 0, stream>>>(hist, total);
    k2b_scan<<<1, 512, 0, stream>>>(total, basearr);
    k3_scatter<<<NBLK1, 256, 0, stream>>>(ei, hist, basearr, ebuf);
    k4_fine<<<NBUCK, 256, 0, stream>>>(ebuf, basearr, csr_src, rowptr, dinv);

    layer0_k<<<NB_GRAPHS, 512, 0, stream>>>(x, gstart, gn0w, gn0b, gn0a, W1, dinv, B, spill16);
    aggregate_h_k<<<25000, 256, 0, stream>>>(B, rowptr, csr_src, dinv, b1, A);
    normlin_k<<<NB_GRAPHS, 512, 0, stream>>>(A, gstart, gn1w, gn1b, gn1a, W2, dinv, B);
    aggregate_h_k<<<25000, 256, 0, stream>>>(B, rowptr, csr_src, dinv, b2, A);
    normlin_k<<<NB_GRAPHS, 512, 0, stream>>>(A, gstart, gn2w, gn2b, gn2a, W3, dinv, B);
    aggregate_h_k<<<25000, 256, 0, stream>>>(B, rowptr, csr_src, dinv, b3, A);
    pool_head_k<<<NB_GRAPHS, 256, 0, stream>>>(A, gstart, Wd, bd, Wo, bo, (float*)d_out);
}

// Round 9
// 333.845 us; speedup vs baseline: 1.6845x; 1.0536x over previous
//
#include <hip/hip_runtime.h>
#include <hip/hip_fp16.h>
#include <math.h>

#define NB_NODES 100000
#define NB_EDGES 1600000
#define NB_GRAPHS 1000
#define CAP 232
#define NBLK1 400      // coarse pass blocks
#define CHUNK 4000     // edges per coarse block (NBLK1*CHUNK == NB_EDGES)
#define NBUCK 391      // ceil(NB_NODES/256) coarse buckets (dst >> 8)
#define BCAP 4608      // max edges per bucket (mean 4096, sigma 64, +8 sigma)
constexpr float GN_EPS = 1e-5f;

// ---- K1: per-block LDS histogram over coarse buckets + gstart (blocks 0-3) ----
__global__ __launch_bounds__(256) void k1_hist(const int* __restrict__ dst,
    int* __restrict__ hist, const int* __restrict__ batch, int* __restrict__ gstart) {
    __shared__ int h[NBUCK];
    int tid = threadIdx.x;
    for (int i = tid; i < NBUCK; i += 256) h[i] = 0;
    if (blockIdx.x < 4) {
        int g = blockIdx.x * 256 + tid;
        if (g <= NB_GRAPHS) {
            int lo = 0, hi = NB_NODES;
            while (lo < hi) {
                int mid = (lo + hi) >> 1;
                if (batch[mid] < g) lo = mid + 1; else hi = mid;
            }
            gstart[g] = lo;
        }
    }
    __syncthreads();
    int base = blockIdx.x * CHUNK;
    for (int i = tid; i < CHUNK; i += 256) atomicAdd(&h[dst[base + i] >> 8], 1);
    __syncthreads();
    for (int i = tid; i < NBUCK; i += 256) hist[blockIdx.x * NBUCK + i] = h[i];
}

// ---- K2a: per bucket, exclusive scan across the 400 blocks; emit totals ----
__global__ __launch_bounds__(512) void k2a_scan(int* __restrict__ hist,
                                                int* __restrict__ total) {
    __shared__ int s[512];
    int b = blockIdx.x;  // bucket
    int tid = threadIdx.x;
    int v = (tid < NBLK1) ? hist[tid * NBUCK + b] : 0;
    s[tid] = v;
    __syncthreads();
    for (int o = 1; o < 512; o <<= 1) {
        int t = (tid >= o) ? s[tid - o] : 0;
        __syncthreads();
        s[tid] += t;
        __syncthreads();
    }
    if (tid < NBLK1) hist[tid * NBUCK + b] = s[tid] - v;  // exclusive prefix in place
    if (tid == 511) total[b] = s[511];
}

// ---- K2b: exclusive scan of bucket totals -> base[NBUCK+1] ----
__global__ __launch_bounds__(512) void k2b_scan(const int* __restrict__ total,
                                                int* __restrict__ base) {
    __shared__ int s[512];
    int tid = threadIdx.x;
    int v = (tid < NBUCK) ? total[tid] : 0;
    s[tid] = v;
    __syncthreads();
    for (int o = 1; o < 512; o <<= 1) {
        int t = (tid >= o) ? s[tid - o] : 0;
        __syncthreads();
        s[tid] += t;
        __syncthreads();
    }
    if (tid < NBUCK) base[tid] = s[tid] - v;
    if (tid == NBUCK) base[NBUCK] = NB_EDGES;
}

// ---- K3: scatter packed edges into bucket-contiguous runs (LDS cursors) ----
__global__ __launch_bounds__(256) void k3_scatter(const int* __restrict__ ei,
    const int* __restrict__ hist, const int* __restrict__ base,
    unsigned int* __restrict__ ebuf) {
    __shared__ int cur[NBUCK];
    int tid = threadIdx.x;
    for (int i = tid; i < NBUCK; i += 256)
        cur[i] = base[i] + hist[blockIdx.x * NBUCK + i];
    __syncthreads();
    int eb = blockIdx.x * CHUNK;
    for (int i = tid; i < CHUNK; i += 256) {
        int e = eb + i;
        int sidx = ei[e];
        int d = ei[NB_EDGES + e];
        int pos = atomicAdd(&cur[d >> 8], 1);
        ebuf[pos] = (unsigned int)sidx | ((unsigned int)(d & 255) << 24);
    }
}

// ---- K4: per-bucket fine CSR in LDS; coalesced csr_src/rowptr/dinv writes ----
__global__ __launch_bounds__(256) void k4_fine(const unsigned int* __restrict__ ebuf,
    const int* __restrict__ base, int* __restrict__ csr_src, int* __restrict__ rowptr,
    float* __restrict__ dinv) {
    __shared__ unsigned int epk[BCAP];
    __shared__ int outb[BCAP];
    __shared__ int cnt[256];
    __shared__ int sbuf[256];
    __shared__ int cur2[256];
    int b = blockIdx.x;
    int tid = threadIdx.x;
    int eb = base[b], ee = base[b + 1];
    int m = ee - eb;
    if (m > BCAP) m = BCAP;  // memory-safety clamp (never expected)
    for (int i = tid; i < m; i += 256) epk[i] = ebuf[eb + i];
    cnt[tid] = 0;
    __syncthreads();
    for (int i = tid; i < m; i += 256) atomicAdd(&cnt[epk[i] >> 24], 1);
    __syncthreads();
    int c = cnt[tid];
    sbuf[tid] = c;
    __syncthreads();
    for (int o = 1; o < 256; o <<= 1) {
        int t = (tid >= o) ? sbuf[tid - o] : 0;
        __syncthreads();
        sbuf[tid] += t;
        __syncthreads();
    }
    int off = sbuf[tid] - c;  // exclusive scan
    cur2[tid] = off;
    __syncthreads();
    for (int i = tid; i < m; i += 256) {
        unsigned int p = epk[i];
        int r = atomicAdd(&cur2[p >> 24], 1);
        outb[r] = (int)(p & 0x00FFFFFFu);
    }
    __syncthreads();
    for (int i = tid; i < m; i += 256) csr_src[eb + i] = outb[i];
    int node = b * 256 + tid;
    if (node < NB_NODES) {
        rowptr[node] = eb + off;
        dinv[node] = rsqrtf((float)(c + 1));
    }
    if (b == 0 && tid == 0) rowptr[NB_NODES] = NB_EDGES;
}

// ---------------- fp16 helpers ----------------
union HU {
    uint4 u;
    __half2 h[4];
};

__device__ __forceinline__ void pkacc(__half2* a, uint4 v) {
    HU x; x.u = v;
    a[0] = __hadd2(a[0], x.h[0]);
    a[1] = __hadd2(a[1], x.h[1]);
    a[2] = __hadd2(a[2], x.h[2]);
    a[3] = __hadd2(a[3], x.h[3]);
}

__device__ __forceinline__ __half2 shxor_h2(__half2 v, int m) {
    union { __half2 h; int i; } u;
    u.h = v;
    u.i = __shfl_xor(u.i, m, 64);
    return u.h;
}

// --- aggregate: 2 seq nodes/wave, 8 lanes x uint4, depth-2 pipeline, fp16 pk acc ---
// hs rows prescaled by dinv[src]. out = relu(dinv[dst]*(self + sum_src) + bias), fp16
// Per-lane fp16 add chain = tb (~deg/8 ~ 2) + 3 reduction levels -> error ~6e-4.
__global__ __launch_bounds__(256) void aggregate_h_k(const __half* __restrict__ hs,
    const int* __restrict__ rowptr, const int* __restrict__ csr_src,
    const float* __restrict__ dinv, const float* __restrict__ bias,
    __half* __restrict__ out) {
    const uint4* hsv = (const uint4*)hs;  // row = 8 uint4 (64 fp16)
    int wv = blockIdx.x * 4 + (threadIdx.x >> 6);
    int lane = threadIdx.x & 63;
    int f8 = lane & 7;   // 16B chunk: features [f8*8, f8*8+8)
    int e8 = lane >> 3;  // edge slot 0..7
    const float4* b4 = (const float4*)bias;
    float4 blo = b4[f8 * 2], bhi = b4[f8 * 2 + 1];
    const uint4 Z = {0u, 0u, 0u, 0u};
#pragma unroll
    for (int nn = 0; nn < 2; nn++) {
        int node = __builtin_amdgcn_readfirstlane(wv * 2 + nn);
        int s = rowptr[node], e = rowptr[node + 1];   // scalar loads
        int len = e - s;
        int nb = len >> 3;
        int rem = len & 7;
        int tb = nb + (rem ? 1 : 0);
        int my = s + e8;
        __half2 acc[4];
        acc[0] = acc[1] = acc[2] = acc[3] = __half2{__half(0.f), __half(0.f)};
        if (e8 == 0) pkacc(acc, hsv[(size_t)node * 8 + f8]);  // self term
        int i0 = -1, i1 = -1;
        if (tb > 0 && (0 < nb || e8 < rem)) i0 = csr_src[my];
        if (tb > 1 && (1 < nb || e8 < rem)) i1 = csr_src[my + 8];
        uint4 v0 = Z;
        if (i0 >= 0) v0 = hsv[(size_t)i0 * 8 + f8];
        for (int b = 0; b + 2 < tb; b++) {
            uint4 v1 = Z;
            if (i1 >= 0) v1 = hsv[(size_t)i1 * 8 + f8];
            int b2 = b + 2;
            int i2 = -1;
            if (b2 < nb || (b2 == nb && e8 < rem)) i2 = csr_src[my + b2 * 8];
            pkacc(acc, v0);
            v0 = v1; i0 = i1; i1 = i2;
        }
        if (tb > 0) pkacc(acc, v0);
        if (tb > 1) {
            uint4 v = Z;
            if (i1 >= 0) v = hsv[(size_t)i1 * 8 + f8];
            pkacc(acc, v);
        }
        // packed fp16 cross-lane reduce over the 8 edge slots
#pragma unroll
        for (int c = 0; c < 4; c++) {
            __half2 t = acc[c];
            t = __hadd2(t, shxor_h2(t, 8));
            t = __hadd2(t, shxor_h2(t, 16));
            t = __hadd2(t, shxor_h2(t, 32));
            acc[c] = t;
        }
        if (e8 == 0) {
            float dn = dinv[node];  // scalar load
            float2 f0 = __half22float2(acc[0]);
            float2 f1 = __half22float2(acc[1]);
            float2 f2 = __half22float2(acc[2]);
            float2 f3 = __half22float2(acc[3]);
            float r[8];
            r[0] = fmaf(f0.x, dn, blo.x); r[1] = fmaf(f0.y, dn, blo.y);
            r[2] = fmaf(f1.x, dn, blo.z); r[3] = fmaf(f1.y, dn, blo.w);
            r[4] = fmaf(f2.x, dn, bhi.x); r[5] = fmaf(f2.y, dn, bhi.y);
            r[6] = fmaf(f3.x, dn, bhi.z); r[7] = fmaf(f3.y, dn, bhi.w);
#pragma unroll
            for (int c = 0; c < 8; c++) r[c] = r[c] > 0.f ? r[c] : 0.f;
            HU o;
            o.h[0] = __floats2half2_rn(r[0], r[1]);
            o.h[1] = __floats2half2_rn(r[2], r[3]);
            o.h[2] = __floats2half2_rn(r[4], r[5]);
            o.h[3] = __floats2half2_rn(r[6], r[7]);
            ((uint4*)out)[(size_t)node * 8 + f8] = o.u;
        }
    }
}

// ------- normlin: GraphNorm(64) single-pass stats + linear 64x64 + dinv -----------
__global__ __launch_bounds__(512) void normlin_k(const __half* __restrict__ A,
    const int* __restrict__ gstart, const float* __restrict__ gw,
    const float* __restrict__ gb, const float* __restrict__ ga,
    const float* __restrict__ W, const float* __restrict__ dinv,
    __half* __restrict__ out) {
    __shared__ float sW[64 * 64];
    __shared__ float red[512], red2[512];
    __shared__ float sam[64], ssc[64];
    __shared__ float srow[8 * 64];
    int tid = threadIdx.x, lane = tid & 63, wid = tid >> 6;
    int g = blockIdx.x;
    int s = gstart[g], e = gstart[g + 1], cnt = e - s;
    float cntf = (float)(cnt > 1 ? cnt : 1);
    for (int i = tid; i < 64 * 64; i += 512) sW[i] = W[i];
    float sum = 0.f, sq = 0.f;
    for (int i = s + wid; i < e; i += 8) {
        float v = __half2float(A[(size_t)i * 64 + lane]);
        sum += v;
        sq = fmaf(v, v, sq);
    }
    red[tid] = sum; red2[tid] = sq;
    __syncthreads();
    for (int st = 4; st > 0; st >>= 1) {
        if (wid < st) { red[tid] += red[tid + st * 64]; red2[tid] += red2[tid + st * 64]; }
        __syncthreads();
    }
    if (tid < 64) {
        float m = red[tid] / cntf, q = red2[tid] / cntf;
        float am = ga[tid] * m;
        float var = q - 2.f * am * m + am * am;
        sam[tid] = am;
        ssc[tid] = gw[tid] * rsqrtf(var + GN_EPS);
    }
    __syncthreads();
    float am = sam[lane], sc = ssc[lane], bb = gb[lane];
    for (int i = s + wid; i < e; i += 8) {
        float nv = (__half2float(A[(size_t)i * 64 + lane]) - am) * sc + bb;
        srow[wid * 64 + lane] = nv;
        float acc = 0.f;
#pragma unroll
        for (int k = 0; k < 64; k++) acc = fmaf(srow[wid * 64 + k], sW[k * 64 + lane], acc);
        out[(size_t)i * 64 + lane] = __float2half(acc * dinv[i]);
    }
}

// ---------------- layer0: GraphNorm(16) + linear 16->64 (block per graph) ---------
__device__ __forceinline__ void l0_body(float* rows, int cnt, int s,
    const float* __restrict__ x, const float* __restrict__ gw,
    const float* __restrict__ gb, const float* __restrict__ ga,
    const float* sW, const float* __restrict__ dinv, __half* __restrict__ hs_out,
    float* red, float* red2, float* sstat, float* sscale, int tid) {
    int f = tid & 15, r = tid >> 4;
    int lane = tid & 63, wid = tid >> 6;
    float cntf = (float)(cnt > 1 ? cnt : 1);
    float sum = 0.f, sq = 0.f;
    for (int i = r; i < cnt; i += 32) {
        float v = x[(size_t)(s + i) * 16 + f];
        rows[i * 16 + f] = v;
        sum += v;
        sq = fmaf(v, v, sq);
    }
    red[tid] = sum; red2[tid] = sq;
    __syncthreads();
    for (int st = 16; st > 0; st >>= 1) {
        if (r < st) { red[tid] += red[tid + st * 16]; red2[tid] += red2[tid + st * 16]; }
        __syncthreads();
    }
    if (tid < 16) {
        float m = red[tid] / cntf, q = red2[tid] / cntf;
        float am = ga[tid] * m;
        sstat[tid] = am;
        sscale[tid] = gw[tid] * rsqrtf(q - 2.f * am * m + am * am + GN_EPS);
    }
    __syncthreads();
    float am = sstat[f], sc = sscale[f], bb = gb[f];
    for (int i = r; i < cnt; i += 32) rows[i * 16 + f] = (rows[i * 16 + f] - am) * sc + bb;
    __syncthreads();
    for (int i = wid; i < cnt; i += 8) {
        float acc = 0.f;
#pragma unroll
        for (int k = 0; k < 16; k++) acc = fmaf(rows[i * 16 + k], sW[k * 64 + lane], acc);
        hs_out[(size_t)(s + i) * 64 + lane] = __float2half(acc * dinv[s + i]);
    }
}

__global__ __launch_bounds__(512) void layer0_k(const float* __restrict__ x,
    const int* __restrict__ gstart, const float* __restrict__ gw,
    const float* __restrict__ gb, const float* __restrict__ ga,
    const float* __restrict__ W, const float* __restrict__ dinv,
    __half* __restrict__ hs_out, float* __restrict__ spill16) {
    __shared__ float sRows[CAP * 16];
    __shared__ float sW[16 * 64];
    __shared__ float red[512], red2[512];
    __shared__ float sstat[16], sscale[16];
    int tid = threadIdx.x;
    int g = blockIdx.x;
    int s = gstart[g], e = gstart[g + 1], cnt = e - s;
    for (int i = tid; i < 16 * 64; i += 512) sW[i] = W[i];
    __syncthreads();
    if (cnt <= CAP)
        l0_body(sRows, cnt, s, x, gw, gb, ga, sW, dinv, hs_out, red, red2, sstat, sscale, tid);
    else
        l0_body(spill16 + (size_t)s * 16, cnt, s, x, gw, gb, ga, sW, dinv, hs_out, red, red2, sstat, sscale, tid);
}

// ---------------- Pool + MLP head + softmax: block per graph ----------------
__global__ void pool_head_k(const __half* __restrict__ x, const int* __restrict__ gstart,
                            const float* __restrict__ Wd, const float* __restrict__ bd,
                            const float* __restrict__ Wo, const float* __restrict__ bo,
                            float* __restrict__ out) {
    __shared__ float red[256];
    __shared__ float sp[64];
    __shared__ float sh[64];
    __shared__ float sl[2];
    int g = blockIdx.x;
    int s = gstart[g], e = gstart[g + 1];
    int cnt = e - s;
    float cntf = (float)(cnt > 1 ? cnt : 1);
    int tid = threadIdx.x;
    int f = tid & 63, r = tid >> 6;
    float sum = 0.f;
    for (int i = s + r; i < e; i += 4) sum += __half2float(x[(size_t)i * 64 + f]);
    red[tid] = sum;
    __syncthreads();
    for (int st = 2; st > 0; st >>= 1) {
        if (r < st) red[tid] += red[tid + st * 64];
        __syncthreads();
    }
    if (tid < 64) sp[tid] = red[tid] / cntf;
    __syncthreads();
    if (tid < 64) {
        float acc = bd[tid];
        for (int k = 0; k < 64; k++) acc = fmaf(sp[k], Wd[k * 64 + tid], acc);
        sh[tid] = acc > 0.f ? acc : 0.f;
    }
    __syncthreads();
    if (tid < 2) {
        float l = bo[tid];
        for (int k = 0; k < 64; k++) l = fmaf(sh[k], Wo[k * 2 + tid], l);
        sl[tid] = l;
    }
    __syncthreads();
    if (tid < 2) {
        float m = fmaxf(sl[0], sl[1]);
        float e0 = expf(sl[0] - m), e1 = expf(sl[1] - m);
        out[g * 2 + tid] = (tid == 0 ? e0 : e1) / (e0 + e1);
    }
}

extern "C" void kernel_launch(void* const* d_in, const int* in_sizes, int n_in,
                              void* d_out, int out_size, void* d_ws, size_t ws_size,
                              hipStream_t stream) {
    const float* x    = (const float*)d_in[0];
    const int* ei     = (const int*)d_in[1];
    const int* batch  = (const int*)d_in[2];
    const float* gn0w = (const float*)d_in[3];
    const float* gn0b = (const float*)d_in[4];
    const float* gn0a = (const float*)d_in[5];
    const float* W1   = (const float*)d_in[6];
    const float* b1   = (const float*)d_in[7];
    const float* gn1w = (const float*)d_in[8];
    const float* gn1b = (const float*)d_in[9];
    const float* gn1a = (const float*)d_in[10];
    const float* W2   = (const float*)d_in[11];
    const float* b2   = (const float*)d_in[12];
    const float* gn2w = (const float*)d_in[13];
    const float* gn2b = (const float*)d_in[14];
    const float* gn2a = (const float*)d_in[15];
    const float* W3   = (const float*)d_in[16];
    const float* b3   = (const float*)d_in[17];
    const float* Wd   = (const float*)d_in[18];
    const float* bd   = (const float*)d_in[19];
    const float* Wo   = (const float*)d_in[20];
    const float* bo   = (const float*)d_in[21];

    char* p = (char*)d_ws;
    auto alloc = [&](size_t bytes) -> void* {
        void* r = (void*)p;
        p += (bytes + 255) & ~(size_t)255;
        return r;
    };
    __half* A        = (__half*)alloc((size_t)NB_NODES * 64 * 2);
    __half* B        = (__half*)alloc((size_t)NB_NODES * 64 * 2);
    int* rowptr      = (int*)alloc((size_t)(NB_NODES + 1) * 4);
    unsigned* ebuf   = (unsigned*)alloc((size_t)NB_EDGES * 4);
    int* csr_src     = (int*)alloc((size_t)NB_EDGES * 4);
    int* hist        = (int*)alloc((size_t)NBLK1 * NBUCK * 4);
    int* total       = (int*)alloc((size_t)NBUCK * 4);
    int* basearr     = (int*)alloc((size_t)(NBUCK + 1) * 4);
    float* dinv      = (float*)alloc((size_t)NB_NODES * 4);
    int* gstart      = (int*)alloc((size_t)(NB_GRAPHS + 1) * 4);
    float* spill16   = (float*)alloc((size_t)NB_NODES * 16 * 4);

    k1_hist<<<NBLK1, 256, 0, stream>>>(ei + NB_EDGES, hist, batch, gstart);
    k2a_scan<<<NBUCK, 512, 0, stream>>>(hist, total);
    k2b_scan<<<1, 512, 0, stream>>>(total, basearr);
    k3_scatter<<<NBLK1, 256, 0, stream>>>(ei, hist, basearr, ebuf);
    k4_fine<<<NBUCK, 256, 0, stream>>>(ebuf, basearr, csr_src, rowptr, dinv);

    layer0_k<<<NB_GRAPHS, 512, 0, stream>>>(x, gstart, gn0w, gn0b, gn0a, W1, dinv, B, spill16);
    aggregate_h_k<<<12500, 256, 0, stream>>>(B, rowptr, csr_src, dinv, b1, A);
    normlin_k<<<NB_GRAPHS, 512, 0, stream>>>(A, gstart, gn1w, gn1b, gn1a, W2, dinv, B);
    aggregate_h_k<<<12500, 256, 0, stream>>>(B, rowptr, csr_src, dinv, b2, A);
    normlin_k<<<NB_GRAPHS, 512, 0, stream>>>(A, gstart, gn2w, gn2b, gn2a, W3, dinv, B);
    aggregate_h_k<<<12500, 256, 0, stream>>>(B, rowptr, csr_src, dinv, b3, A);
    pool_head_k<<<NB_GRAPHS, 256, 0, stream>>>(A, gstart, Wd, bd, Wo, bo, (float*)d_out);
}

// Round 10
// 321.461 us; speedup vs baseline: 1.7493x; 1.0385x over previous
//
#include <hip/hip_runtime.h>
#include <hip/hip_fp16.h>
#include <math.h>

#define NB_NODES 100000
#define NB_EDGES 1600000
#define NB_GRAPHS 1000
#define CAP 232
#define NBLK1 400      // coarse pass blocks
#define CHUNK 4000     // edges per coarse block (NBLK1*CHUNK == NB_EDGES)
#define NBUCK 391      // ceil(NB_NODES/256) coarse buckets (dst >> 8)
#define BCAP 4608      // max edges per bucket (mean 4096, sigma 64, +8 sigma)
constexpr float GN_EPS = 1e-5f;

// ---- K1: per-block LDS histogram over coarse buckets + gstart (blocks 0-3) ----
__global__ __launch_bounds__(256) void k1_hist(const int* __restrict__ dst,
    int* __restrict__ hist, const int* __restrict__ batch, int* __restrict__ gstart) {
    __shared__ int h[NBUCK];
    int tid = threadIdx.x;
    for (int i = tid; i < NBUCK; i += 256) h[i] = 0;
    if (blockIdx.x < 4) {
        int g = blockIdx.x * 256 + tid;
        if (g <= NB_GRAPHS) {
            int lo = 0, hi = NB_NODES;
            while (lo < hi) {
                int mid = (lo + hi) >> 1;
                if (batch[mid] < g) lo = mid + 1; else hi = mid;
            }
            gstart[g] = lo;
        }
    }
    __syncthreads();
    int base = blockIdx.x * CHUNK;
    for (int i = tid; i < CHUNK; i += 256) atomicAdd(&h[dst[base + i] >> 8], 1);
    __syncthreads();
    for (int i = tid; i < NBUCK; i += 256) hist[blockIdx.x * NBUCK + i] = h[i];
}

// ---- K2a: per bucket, exclusive scan across the 400 blocks; emit totals ----
__global__ __launch_bounds__(512) void k2a_scan(int* __restrict__ hist,
                                                int* __restrict__ total) {
    __shared__ int s[512];
    int b = blockIdx.x;  // bucket
    int tid = threadIdx.x;
    int v = (tid < NBLK1) ? hist[tid * NBUCK + b] : 0;
    s[tid] = v;
    __syncthreads();
    for (int o = 1; o < 512; o <<= 1) {
        int t = (tid >= o) ? s[tid - o] : 0;
        __syncthreads();
        s[tid] += t;
        __syncthreads();
    }
    if (tid < NBLK1) hist[tid * NBUCK + b] = s[tid] - v;  // exclusive prefix in place
    if (tid == 511) total[b] = s[511];
}

// ---- K2b: exclusive scan of bucket totals -> base[NBUCK+1] ----
__global__ __launch_bounds__(512) void k2b_scan(const int* __restrict__ total,
                                                int* __restrict__ base) {
    __shared__ int s[512];
    int tid = threadIdx.x;
    int v = (tid < NBUCK) ? total[tid] : 0;
    s[tid] = v;
    __syncthreads();
    for (int o = 1; o < 512; o <<= 1) {
        int t = (tid >= o) ? s[tid - o] : 0;
        __syncthreads();
        s[tid] += t;
        __syncthreads();
    }
    if (tid < NBUCK) base[tid] = s[tid] - v;
    if (tid == NBUCK) base[NBUCK] = NB_EDGES;
}

// ---- K3: scatter packed edges into bucket-contiguous runs (LDS cursors) ----
__global__ __launch_bounds__(256) void k3_scatter(const int* __restrict__ ei,
    const int* __restrict__ hist, const int* __restrict__ base,
    unsigned int* __restrict__ ebuf) {
    __shared__ int cur[NBUCK];
    int tid = threadIdx.x;
    for (int i = tid; i < NBUCK; i += 256)
        cur[i] = base[i] + hist[blockIdx.x * NBUCK + i];
    __syncthreads();
    int eb = blockIdx.x * CHUNK;
    for (int i = tid; i < CHUNK; i += 256) {
        int e = eb + i;
        int sidx = ei[e];
        int d = ei[NB_EDGES + e];
        int pos = atomicAdd(&cur[d >> 8], 1);
        ebuf[pos] = (unsigned int)sidx | ((unsigned int)(d & 255) << 24);
    }
}

// ---- K4: per-bucket fine CSR in LDS; coalesced csr_src/rowptr/dinv writes ----
__global__ __launch_bounds__(256) void k4_fine(const unsigned int* __restrict__ ebuf,
    const int* __restrict__ base, int* __restrict__ csr_src, int* __restrict__ rowptr,
    float* __restrict__ dinv) {
    __shared__ unsigned int epk[BCAP];
    __shared__ int outb[BCAP];
    __shared__ int cnt[256];
    __shared__ int sbuf[256];
    __shared__ int cur2[256];
    int b = blockIdx.x;
    int tid = threadIdx.x;
    int eb = base[b], ee = base[b + 1];
    int m = ee - eb;
    if (m > BCAP) m = BCAP;  // memory-safety clamp (never expected)
    for (int i = tid; i < m; i += 256) epk[i] = ebuf[eb + i];
    cnt[tid] = 0;
    __syncthreads();
    for (int i = tid; i < m; i += 256) atomicAdd(&cnt[epk[i] >> 24], 1);
    __syncthreads();
    int c = cnt[tid];
    sbuf[tid] = c;
    __syncthreads();
    for (int o = 1; o < 256; o <<= 1) {
        int t = (tid >= o) ? sbuf[tid - o] : 0;
        __syncthreads();
        sbuf[tid] += t;
        __syncthreads();
    }
    int off = sbuf[tid] - c;  // exclusive scan
    cur2[tid] = off;
    __syncthreads();
    for (int i = tid; i < m; i += 256) {
        unsigned int p = epk[i];
        int r = atomicAdd(&cur2[p >> 24], 1);
        outb[r] = (int)(p & 0x00FFFFFFu);
    }
    __syncthreads();
    for (int i = tid; i < m; i += 256) csr_src[eb + i] = outb[i];
    int node = b * 256 + tid;
    if (node < NB_NODES) {
        rowptr[node] = eb + off;
        dinv[node] = rsqrtf((float)(c + 1));
    }
    if (b == 0 && tid == 0) rowptr[NB_NODES] = NB_EDGES;
}

// ---------------- fp16 helpers ----------------
union HU {
    uint4 u;
    __half2 h[4];
};

__device__ __forceinline__ void pkacc(__half2* a, uint4 v) {
    HU x; x.u = v;
    a[0] = __hadd2(a[0], x.h[0]);
    a[1] = __hadd2(a[1], x.h[1]);
    a[2] = __hadd2(a[2], x.h[2]);
    a[3] = __hadd2(a[3], x.h[3]);
}

__device__ __forceinline__ __half2 shxor_h2(__half2 v, int m) {
    union { __half2 h; int i; } u;
    u.h = v;
    u.i = __shfl_xor(u.i, m, 64);
    return u.h;
}

// --- aggregate: 2 nodes/wave; ONE coalesced idx load covers deg<=64; all gathers
// issued back-to-back (blocks 0..3 in registers, 4..7 via shuffle-loop, >8 direct).
// hs rows prescaled by dinv[src]. out = relu(dinv[dst]*(self + sum_src) + bias), fp16
__global__ __launch_bounds__(256) void aggregate_h_k(const __half* __restrict__ hs,
    const int* __restrict__ rowptr, const int* __restrict__ csr_src,
    const float* __restrict__ dinv, const float* __restrict__ bias,
    __half* __restrict__ out) {
    const uint4* hsv = (const uint4*)hs;  // row = 8 uint4 (64 fp16)
    int wv = blockIdx.x * 4 + (threadIdx.x >> 6);
    int lane = threadIdx.x & 63;
    int f8 = lane & 7;   // 16B chunk: features [f8*8, f8*8+8)
    int e8 = lane >> 3;  // edge slot 0..7
    int n0 = __builtin_amdgcn_readfirstlane(wv * 2);
    int n1 = n0 + 1;
    int s0 = rowptr[n0], e0 = rowptr[n0 + 1], e1 = rowptr[n1 + 1];  // scalar loads
    int s1 = e0;  // rowptr is contiguous
    int d0 = e0 - s0, d1 = e1 - s1;
    const uint4 Z = {0u, 0u, 0u, 0u};
    // one coalesced index load per node: lane i -> edge i (valid for deg<=64)
    int idx0 = (lane < d0) ? csr_src[s0 + lane] : -1;
    int idx1 = (lane < d1) ? csr_src[s1 + lane] : -1;
    // self rows issued early
    uint4 self0 = Z, self1 = Z;
    if (e8 == 0) self0 = hsv[(size_t)n0 * 8 + f8];
    if (e8 == 1) self1 = hsv[(size_t)n1 * 8 + f8];
    // bulk gather: blocks 0..3 of both nodes, all loads in flight
    uint4 g0[4], g1[4];
#pragma unroll
    for (int b = 0; b < 4; b++) {
        int u = __shfl(idx0, b * 8 + e8, 64);
        g0[b] = Z;
        if (u >= 0) g0[b] = hsv[(size_t)u * 8 + f8];
        int v = __shfl(idx1, b * 8 + e8, 64);
        g1[b] = Z;
        if (v >= 0) g1[b] = hsv[(size_t)v * 8 + f8];
    }
    __half2 acc0[4], acc1[4];
    acc0[0] = acc0[1] = acc0[2] = acc0[3] = __half2{__half(0.f), __half(0.f)};
    acc1[0] = acc1[1] = acc1[2] = acc1[3] = __half2{__half(0.f), __half(0.f)};
    pkacc(acc0, self0);
    pkacc(acc1, self1);
#pragma unroll
    for (int b = 0; b < 4; b++) { pkacc(acc0, g0[b]); pkacc(acc1, g1[b]); }
    // rare: deg in (32,64] -> blocks 4..7 from the same idx vector
    int tb0 = (d0 + 7) >> 3, tb1 = (d1 + 7) >> 3;
    for (int b = 4; b < tb0 && b < 8; b++) {
        int u = __shfl(idx0, b * 8 + e8, 64);
        if (u >= 0) pkacc(acc0, hsv[(size_t)u * 8 + f8]);
    }
    for (int b = 4; b < tb1 && b < 8; b++) {
        int v = __shfl(idx1, b * 8 + e8, 64);
        if (v >= 0) pkacc(acc1, hsv[(size_t)v * 8 + f8]);
    }
    // ~never: deg > 64
    for (int b = 8; b < tb0; b++) {
        int j = s0 + b * 8 + e8;
        if (j < e0) { int u = csr_src[j]; pkacc(acc0, hsv[(size_t)u * 8 + f8]); }
    }
    for (int b = 8; b < tb1; b++) {
        int j = s1 + b * 8 + e8;
        if (j < e1) { int v = csr_src[j]; pkacc(acc1, hsv[(size_t)v * 8 + f8]); }
    }
    // packed fp16 cross-lane reduce over the 8 edge slots
#pragma unroll
    for (int c = 0; c < 4; c++) {
        __half2 t = acc0[c];
        t = __hadd2(t, shxor_h2(t, 8));
        t = __hadd2(t, shxor_h2(t, 16));
        t = __hadd2(t, shxor_h2(t, 32));
        acc0[c] = t;
        __half2 u = acc1[c];
        u = __hadd2(u, shxor_h2(u, 8));
        u = __hadd2(u, shxor_h2(u, 16));
        u = __hadd2(u, shxor_h2(u, 32));
        acc1[c] = u;
    }
    if (e8 < 2) {
        int node = (e8 == 0) ? n0 : n1;
        const __half2* acc = (e8 == 0) ? acc0 : acc1;
        float dn = dinv[node];
        const float4* b4 = (const float4*)bias;
        float4 blo = b4[f8 * 2], bhi = b4[f8 * 2 + 1];
        float2 f0 = __half22float2(acc[0]);
        float2 f1 = __half22float2(acc[1]);
        float2 f2 = __half22float2(acc[2]);
        float2 f3 = __half22float2(acc[3]);
        float r[8];
        r[0] = fmaf(f0.x, dn, blo.x); r[1] = fmaf(f0.y, dn, blo.y);
        r[2] = fmaf(f1.x, dn, blo.z); r[3] = fmaf(f1.y, dn, blo.w);
        r[4] = fmaf(f2.x, dn, bhi.x); r[5] = fmaf(f2.y, dn, bhi.y);
        r[6] = fmaf(f3.x, dn, bhi.z); r[7] = fmaf(f3.y, dn, bhi.w);
#pragma unroll
        for (int c = 0; c < 8; c++) r[c] = r[c] > 0.f ? r[c] : 0.f;
        HU o;
        o.h[0] = __floats2half2_rn(r[0], r[1]);
        o.h[1] = __floats2half2_rn(r[2], r[3]);
        o.h[2] = __floats2half2_rn(r[4], r[5]);
        o.h[3] = __floats2half2_rn(r[6], r[7]);
        ((uint4*)out)[(size_t)node * 8 + f8] = o.u;
    }
}

// ------- normlin: GraphNorm(64) single-pass stats + linear 64x64 + dinv -----------
__global__ __launch_bounds__(512) void normlin_k(const __half* __restrict__ A,
    const int* __restrict__ gstart, const float* __restrict__ gw,
    const float* __restrict__ gb, const float* __restrict__ ga,
    const float* __restrict__ W, const float* __restrict__ dinv,
    __half* __restrict__ out) {
    __shared__ float sW[64 * 64];
    __shared__ float red[512], red2[512];
    __shared__ float sam[64], ssc[64];
    __shared__ float srow[8 * 64];
    int tid = threadIdx.x, lane = tid & 63, wid = tid >> 6;
    int g = blockIdx.x;
    int s = gstart[g], e = gstart[g + 1], cnt = e - s;
    float cntf = (float)(cnt > 1 ? cnt : 1);
    for (int i = tid; i < 64 * 64; i += 512) sW[i] = W[i];
    float sum = 0.f, sq = 0.f;
    for (int i = s + wid; i < e; i += 8) {
        float v = __half2float(A[(size_t)i * 64 + lane]);
        sum += v;
        sq = fmaf(v, v, sq);
    }
    red[tid] = sum; red2[tid] = sq;
    __syncthreads();
    for (int st = 4; st > 0; st >>= 1) {
        if (wid < st) { red[tid] += red[tid + st * 64]; red2[tid] += red2[tid + st * 64]; }
        __syncthreads();
    }
    if (tid < 64) {
        float m = red[tid] / cntf, q = red2[tid] / cntf;
        float am = ga[tid] * m;
        float var = q - 2.f * am * m + am * am;
        sam[tid] = am;
        ssc[tid] = gw[tid] * rsqrtf(var + GN_EPS);
    }
    __syncthreads();
    float am = sam[lane], sc = ssc[lane], bb = gb[lane];
    for (int i = s + wid; i < e; i += 8) {
        float nv = (__half2float(A[(size_t)i * 64 + lane]) - am) * sc + bb;
        srow[wid * 64 + lane] = nv;
        float acc = 0.f;
#pragma unroll
        for (int k = 0; k < 64; k++) acc = fmaf(srow[wid * 64 + k], sW[k * 64 + lane], acc);
        out[(size_t)i * 64 + lane] = __float2half(acc * dinv[i]);
    }
}

// ---------------- layer0: GraphNorm(16) + linear 16->64 (block per graph) ---------
__device__ __forceinline__ void l0_body(float* rows, int cnt, int s,
    const float* __restrict__ x, const float* __restrict__ gw,
    const float* __restrict__ gb, const float* __restrict__ ga,
    const float* sW, const float* __restrict__ dinv, __half* __restrict__ hs_out,
    float* red, float* red2, float* sstat, float* sscale, int tid) {
    int f = tid & 15, r = tid >> 4;
    int lane = tid & 63, wid = tid >> 6;
    float cntf = (float)(cnt > 1 ? cnt : 1);
    float sum = 0.f, sq = 0.f;
    for (int i = r; i < cnt; i += 32) {
        float v = x[(size_t)(s + i) * 16 + f];
        rows[i * 16 + f] = v;
        sum += v;
        sq = fmaf(v, v, sq);
    }
    red[tid] = sum; red2[tid] = sq;
    __syncthreads();
    for (int st = 16; st > 0; st >>= 1) {
        if (r < st) { red[tid] += red[tid + st * 16]; red2[tid] += red2[tid + st * 16]; }
        __syncthreads();
    }
    if (tid < 16) {
        float m = red[tid] / cntf, q = red2[tid] / cntf;
        float am = ga[tid] * m;
        sstat[tid] = am;
        sscale[tid] = gw[tid] * rsqrtf(q - 2.f * am * m + am * am + GN_EPS);
    }
    __syncthreads();
    float am = sstat[f], sc = sscale[f], bb = gb[f];
    for (int i = r; i < cnt; i += 32) rows[i * 16 + f] = (rows[i * 16 + f] - am) * sc + bb;
    __syncthreads();
    for (int i = wid; i < cnt; i += 8) {
        float acc = 0.f;
#pragma unroll
        for (int k = 0; k < 16; k++) acc = fmaf(rows[i * 16 + k], sW[k * 64 + lane], acc);
        hs_out[(size_t)(s + i) * 64 + lane] = __float2half(acc * dinv[s + i]);
    }
}

__global__ __launch_bounds__(512) void layer0_k(const float* __restrict__ x,
    const int* __restrict__ gstart, const float* __restrict__ gw,
    const float* __restrict__ gb, const float* __restrict__ ga,
    const float* __restrict__ W, const float* __restrict__ dinv,
    __half* __restrict__ hs_out, float* __restrict__ spill16) {
    __shared__ float sRows[CAP * 16];
    __shared__ float sW[16 * 64];
    __shared__ float red[512], red2[512];
    __shared__ float sstat[16], sscale[16];
    int tid = threadIdx.x;
    int g = blockIdx.x;
    int s = gstart[g], e = gstart[g + 1], cnt = e - s;
    for (int i = tid; i < 16 * 64; i += 512) sW[i] = W[i];
    __syncthreads();
    if (cnt <= CAP)
        l0_body(sRows, cnt, s, x, gw, gb, ga, sW, dinv, hs_out, red, red2, sstat, sscale, tid);
    else
        l0_body(spill16 + (size_t)s * 16, cnt, s, x, gw, gb, ga, sW, dinv, hs_out, red, red2, sstat, sscale, tid);
}

// ---------------- Pool + MLP head + softmax: block per graph ----------------
__global__ void pool_head_k(const __half* __restrict__ x, const int* __restrict__ gstart,
                            const float* __restrict__ Wd, const float* __restrict__ bd,
                            const float* __restrict__ Wo, const float* __restrict__ bo,
                            float* __restrict__ out) {
    __shared__ float red[256];
    __shared__ float sp[64];
    __shared__ float sh[64];
    __shared__ float sl[2];
    int g = blockIdx.x;
    int s = gstart[g], e = gstart[g + 1];
    int cnt = e - s;
    float cntf = (float)(cnt > 1 ? cnt : 1);
    int tid = threadIdx.x;
    int f = tid & 63, r = tid >> 6;
    float sum = 0.f;
    for (int i = s + r; i < e; i += 4) sum += __half2float(x[(size_t)i * 64 + f]);
    red[tid] = sum;
    __syncthreads();
    for (int st = 2; st > 0; st >>= 1) {
        if (r < st) red[tid] += red[tid + st * 64];
        __syncthreads();
    }
    if (tid < 64) sp[tid] = red[tid] / cntf;
    __syncthreads();
    if (tid < 64) {
        float acc = bd[tid];
        for (int k = 0; k < 64; k++) acc = fmaf(sp[k], Wd[k * 64 + tid], acc);
        sh[tid] = acc > 0.f ? acc : 0.f;
    }
    __syncthreads();
    if (tid < 2) {
        float l = bo[tid];
        for (int k = 0; k < 64; k++) l = fmaf(sh[k], Wo[k * 2 + tid], l);
        sl[tid] = l;
    }
    __syncthreads();
    if (tid < 2) {
        float m = fmaxf(sl[0], sl[1]);
        float e0 = expf(sl[0] - m), e1 = expf(sl[1] - m);
        out[g * 2 + tid] = (tid == 0 ? e0 : e1) / (e0 + e1);
    }
}

extern "C" void kernel_launch(void* const* d_in, const int* in_sizes, int n_in,
                              void* d_out, int out_size, void* d_ws, size_t ws_size,
                              hipStream_t stream) {
    const float* x    = (const float*)d_in[0];
    const int* ei     = (const int*)d_in[1];
    const int* batch  = (const int*)d_in[2];
    const float* gn0w = (const float*)d_in[3];
    const float* gn0b = (const float*)d_in[4];
    const float* gn0a = (const float*)d_in[5];
    const float* W1   = (const float*)d_in[6];
    const float* b1   = (const float*)d_in[7];
    const float* gn1w = (const float*)d_in[8];
    const float* gn1b = (const float*)d_in[9];
    const float* gn1a = (const float*)d_in[10];
    const float* W2   = (const float*)d_in[11];
    const float* b2   = (const float*)d_in[12];
    const float* gn2w = (const float*)d_in[13];
    const float* gn2b = (const float*)d_in[14];
    const float* gn2a = (const float*)d_in[15];
    const float* W3   = (const float*)d_in[16];
    const float* b3   = (const float*)d_in[17];
    const float* Wd   = (const float*)d_in[18];
    const float* bd   = (const float*)d_in[19];
    const float* Wo   = (const float*)d_in[20];
    const float* bo   = (const float*)d_in[21];

    char* p = (char*)d_ws;
    auto alloc = [&](size_t bytes) -> void* {
        void* r = (void*)p;
        p += (bytes + 255) & ~(size_t)255;
        return r;
    };
    __half* A        = (__half*)alloc((size_t)NB_NODES * 64 * 2);
    __half* B        = (__half*)alloc((size_t)NB_NODES * 64 * 2);
    int* rowptr      = (int*)alloc((size_t)(NB_NODES + 1) * 4);
    unsigned* ebuf   = (unsigned*)alloc((size_t)NB_EDGES * 4);
    int* csr_src     = (int*)alloc((size_t)NB_EDGES * 4);
    int* hist        = (int*)alloc((size_t)NBLK1 * NBUCK * 4);
    int* total       = (int*)alloc((size_t)NBUCK * 4);
    int* basearr     = (int*)alloc((size_t)(NBUCK + 1) * 4);
    float* dinv      = (float*)alloc((size_t)NB_NODES * 4);
    int* gstart      = (int*)alloc((size_t)(NB_GRAPHS + 1) * 4);
    float* spill16   = (float*)alloc((size_t)NB_NODES * 16 * 4);

    k1_hist<<<NBLK1, 256, 0, stream>>>(ei + NB_EDGES, hist, batch, gstart);
    k2a_scan<<<NBUCK, 512, 0, stream>>>(hist, total);
    k2b_scan<<<1, 512, 0, stream>>>(total, basearr);
    k3_scatter<<<NBLK1, 256, 0, stream>>>(ei, hist, basearr, ebuf);
    k4_fine<<<NBUCK, 256, 0, stream>>>(ebuf, basearr, csr_src, rowptr, dinv);

    layer0_k<<<NB_GRAPHS, 512, 0, stream>>>(x, gstart, gn0w, gn0b, gn0a, W1, dinv, B, spill16);
    aggregate_h_k<<<12500, 256, 0, stream>>>(B, rowptr, csr_src, dinv, b1, A);
    normlin_k<<<NB_GRAPHS, 512, 0, stream>>>(A, gstart, gn1w, gn1b, gn1a, W2, dinv, B);
    aggregate_h_k<<<12500, 256, 0, stream>>>(B, rowptr, csr_src, dinv, b2, A);
    normlin_k<<<NB_GRAPHS, 512, 0, stream>>>(A, gstart, gn2w, gn2b, gn2a, W3, dinv, B);
    aggregate_h_k<<<12500, 256, 0, stream>>>(B, rowptr, csr_src, dinv, b3, A);
    pool_head_k<<<NB_GRAPHS, 256, 0, stream>>>(A, gstart, Wd, bd, Wo, bo, (float*)d_out);
}